// Round 1
// baseline (943.113 us; speedup 1.0000x reference)
//
#include <hip/hip_runtime.h>

#define N_NODES 50000
#define N_EDGES 800000
#define N_GRAPHS 256
#define F 64

// ---------------- degree ----------------
__global__ __launch_bounds__(256) void deg_count(const int* __restrict__ dst,
                                                 float* __restrict__ deg, int nE) {
    int e = blockIdx.x * blockDim.x + threadIdx.x;
    if (e < nE) atomicAdd(&deg[dst[e]], 1.0f);
}

__global__ __launch_bounds__(256) void deg_finish(const float* __restrict__ deg,
                                                  float* __restrict__ dinv,
                                                  float* __restrict__ invdeg, int n) {
    int i = blockIdx.x * blockDim.x + threadIdx.x;
    if (i < n) {
        float d = deg[i] + 1.0f;     // self-loop
        dinv[i]   = 1.0f / sqrtf(d);
        invdeg[i] = 1.0f / d;
    }
}

// ---------------- GEMM: H[n,64] = X[n,64] @ W[64,64] ----------------
__global__ __launch_bounds__(256) void gemm64(const float* __restrict__ X,
                                              const float* __restrict__ W,
                                              float* __restrict__ H, int n) {
    __shared__ float sW[64][64];   // sW[k][j]
    __shared__ float sX[64][64];   // sX[r][k]; wave reads are broadcast, no conflicts
    int tid = threadIdx.x;
    int base = blockIdx.x * 64;

    for (int i = tid; i < 64 * 64; i += 256) sW[i >> 6][i & 63] = W[i];
    for (int i = tid; i < 64 * 64; i += 256) {
        int r = i >> 6, c = i & 63;
        int node = base + r;
        sX[r][c] = (node < n) ? X[node * 64 + c] : 0.0f;
    }
    __syncthreads();

    int j  = tid & 63;     // feature (lane)
    int r0 = tid >> 6;     // 0..3
    float acc[16];
#pragma unroll
    for (int ii = 0; ii < 16; ii++) acc[ii] = 0.0f;
    for (int k = 0; k < 64; k++) {
        float w = sW[k][j];
#pragma unroll
        for (int ii = 0; ii < 16; ii++)
            acc[ii] += sX[r0 + ii * 4][k] * w;
    }
#pragma unroll
    for (int ii = 0; ii < 16; ii++) {
        int node = base + r0 + ii * 4;
        if (node < n) H[node * 64 + j] = acc[ii];
    }
}

// ---------------- edge scatter: AGG[dst] += H[src] * dinv[src]*dinv[dst] ----------------
__global__ __launch_bounds__(256) void scatter_edges(const int* __restrict__ src,
                                                     const int* __restrict__ dst,
                                                     const float* __restrict__ dinv,
                                                     const float* __restrict__ H,
                                                     float* __restrict__ AGG, int nE) {
    int t = blockIdx.x * blockDim.x + threadIdx.x;
    int e = t >> 6;
    int j = t & 63;
    if (e < nE) {
        int s = src[e], d = dst[e];
        float norm = dinv[s] * dinv[d];
        float v = H[s * 64 + j] * norm;
        atomicAdd(&AGG[d * 64 + j], v);
    }
}

// ---------------- epilogue: H = relu(AGG + H*invdeg[i] + b[j]) (in-place over H) ----------------
__global__ __launch_bounds__(256) void finish_layer(float* __restrict__ H,
                                                    const float* __restrict__ AGG,
                                                    const float* __restrict__ invdeg,
                                                    const float* __restrict__ b, int n) {
    int t = blockIdx.x * blockDim.x + threadIdx.x;
    if (t < n * F) {
        int i = t >> 6, j = t & 63;
        float v = AGG[t] + H[t] * invdeg[i] + b[j];
        H[t] = fmaxf(v, 0.0f);
    }
}

// ---------------- pooling: per-node dot with Wl, scalar atomics into graph bins ----------------
__global__ __launch_bounds__(256) void pool_dot(const float* __restrict__ H,
                                                const int* __restrict__ batch,
                                                const float* __restrict__ Wl,
                                                float* __restrict__ gsum,
                                                float* __restrict__ gcnt, int n) {
    int t = blockIdx.x * blockDim.x + threadIdx.x;
    int node = t >> 6;
    int lane = threadIdx.x & 63;
    if (node < n) {
        float v = H[node * 64 + lane] * Wl[lane];
#pragma unroll
        for (int off = 32; off > 0; off >>= 1) v += __shfl_down(v, off);
        if (lane == 0) {
            int g = batch[node];
            atomicAdd(&gsum[g], v);
            atomicAdd(&gcnt[g], 1.0f);
        }
    }
}

__global__ void final_out(const float* __restrict__ gsum, const float* __restrict__ gcnt,
                          const float* __restrict__ bl, float* __restrict__ out) {
    int g = blockIdx.x * blockDim.x + threadIdx.x;
    if (g < N_GRAPHS) out[g] = gsum[g] / fmaxf(gcnt[g], 1.0f) + bl[0];
}

extern "C" void kernel_launch(void* const* d_in, const int* in_sizes, int n_in,
                              void* d_out, int out_size, void* d_ws, size_t ws_size,
                              hipStream_t stream) {
    const float* x     = (const float*)d_in[0];
    const int*   src   = (const int*)d_in[1];
    const int*   dst   = (const int*)d_in[2];
    const int*   batch = (const int*)d_in[3];
    const float* W1 = (const float*)d_in[4];  const float* b1 = (const float*)d_in[5];
    const float* W2 = (const float*)d_in[6];  const float* b2 = (const float*)d_in[7];
    const float* W3 = (const float*)d_in[8];  const float* b3 = (const float*)d_in[9];
    const float* Wl = (const float*)d_in[10]; const float* bl = (const float*)d_in[11];
    float* out = (float*)d_out;

    float* ws     = (float*)d_ws;
    float* A      = ws;                       // N*F
    float* B      = A + (size_t)N_NODES * F;  // N*F
    float* deg    = B + (size_t)N_NODES * F;  // N
    float* dinv   = deg + N_NODES;            // N
    float* invdeg = dinv + N_NODES;           // N
    float* gsum   = invdeg + N_NODES;         // G
    float* gcnt   = gsum + N_GRAPHS;          // G

    const int GEMM_GRID    = (N_NODES + 63) / 64;          // 782
    const int SCAT_GRID    = (N_EDGES * 64) / 256;         // 200000
    const int ELT_GRID     = (N_NODES * F + 255) / 256;    // 12500
    const int NODEWAVE_GRID = (N_NODES * 64 + 255) / 256;  // 12500

    // degrees
    hipMemsetAsync(deg, 0, N_NODES * sizeof(float), stream);
    deg_count<<<(N_EDGES + 255) / 256, 256, 0, stream>>>(dst, deg, N_EDGES);
    deg_finish<<<(N_NODES + 255) / 256, 256, 0, stream>>>(deg, dinv, invdeg, N_NODES);

    // layer 1: gemm(x->A); scatter(A->B); finish -> A
    gemm64<<<GEMM_GRID, 256, 0, stream>>>(x, W1, A, N_NODES);
    hipMemsetAsync(B, 0, (size_t)N_NODES * F * sizeof(float), stream);
    scatter_edges<<<SCAT_GRID, 256, 0, stream>>>(src, dst, dinv, A, B, N_EDGES);
    finish_layer<<<ELT_GRID, 256, 0, stream>>>(A, B, invdeg, b1, N_NODES);

    // layer 2: gemm(A->B); scatter(B->A); finish -> B
    gemm64<<<GEMM_GRID, 256, 0, stream>>>(A, W2, B, N_NODES);
    hipMemsetAsync(A, 0, (size_t)N_NODES * F * sizeof(float), stream);
    scatter_edges<<<SCAT_GRID, 256, 0, stream>>>(src, dst, dinv, B, A, N_EDGES);
    finish_layer<<<ELT_GRID, 256, 0, stream>>>(B, A, invdeg, b2, N_NODES);

    // layer 3: gemm(B->A); scatter(A->B); finish -> A
    gemm64<<<GEMM_GRID, 256, 0, stream>>>(B, W3, A, N_NODES);
    hipMemsetAsync(B, 0, (size_t)N_NODES * F * sizeof(float), stream);
    scatter_edges<<<SCAT_GRID, 256, 0, stream>>>(src, dst, dinv, A, B, N_EDGES);
    finish_layer<<<ELT_GRID, 256, 0, stream>>>(A, B, invdeg, b3, N_NODES);

    // pooling + head
    hipMemsetAsync(gsum, 0, 2 * N_GRAPHS * sizeof(float), stream);
    pool_dot<<<NODEWAVE_GRID, 256, 0, stream>>>(A, batch, Wl, gsum, gcnt, N_NODES);
    final_out<<<1, 256, 0, stream>>>(gsum, gcnt, bl, out);
}

// Round 2
// 628.913 us; speedup vs baseline: 1.4996x; 1.4996x over previous
//
#include <hip/hip_runtime.h>

#define N_NODES 50000
#define N_EDGES 800000
#define N_GRAPHS 256
#define F 64
#define SCAN_THREADS 1024
#define CHUNK ((N_NODES + SCAN_THREADS - 1) / SCAN_THREADS)

// ---------------- histogram of in-degrees (int) ----------------
__global__ __launch_bounds__(256) void hist_dst(const int* __restrict__ dst,
                                                int* __restrict__ cnt, int nE) {
    int e = blockIdx.x * blockDim.x + threadIdx.x;
    if (e < nE) atomicAdd(&cnt[dst[e]], 1);
}

__global__ __launch_bounds__(256) void deg_finish(const int* __restrict__ cnt,
                                                  float* __restrict__ dinv,
                                                  float* __restrict__ invdeg, int n) {
    int i = blockIdx.x * blockDim.x + threadIdx.x;
    if (i < n) {
        float d = (float)cnt[i] + 1.0f;   // self-loop
        dinv[i]   = 1.0f / sqrtf(d);
        invdeg[i] = 1.0f / d;
    }
}

// ---------------- exclusive scan -> CSR rowptr (+ cursor copy) ----------------
__global__ __launch_bounds__(SCAN_THREADS) void scan_rowptr(const int* __restrict__ cnt,
                                                            int* __restrict__ rowptr,
                                                            int* __restrict__ cursor) {
    __shared__ int ssum[SCAN_THREADS];
    int t = threadIdx.x;
    int lo = t * CHUNK;
    int hi = min(lo + CHUNK, N_NODES);
    int s = 0;
    for (int i = lo; i < hi; i++) s += cnt[i];
    ssum[t] = s;
    __syncthreads();
    for (int off = 1; off < SCAN_THREADS; off <<= 1) {
        int v = (t >= off) ? ssum[t - off] : 0;
        __syncthreads();
        ssum[t] += v;
        __syncthreads();
    }
    int run = (t > 0) ? ssum[t - 1] : 0;  // exclusive prefix of this chunk
    for (int i = lo; i < hi; i++) {
        rowptr[i] = run;
        cursor[i] = run;
        run += cnt[i];
    }
    if (t == SCAN_THREADS - 1) rowptr[N_NODES] = run;
}

// ---------------- bucket edges by dst ----------------
__global__ __launch_bounds__(256) void reorder_edges(const int* __restrict__ src,
                                                     const int* __restrict__ dst,
                                                     int* __restrict__ cursor,
                                                     int* __restrict__ eidx, int nE) {
    int e = blockIdx.x * blockDim.x + threadIdx.x;
    if (e < nE) {
        int d = dst[e];
        int pos = atomicAdd(&cursor[d], 1);
        eidx[pos] = src[e];
    }
}

// ---------------- GEMM: H[n,64] = X[n,64] @ W[64,64] ----------------
__global__ __launch_bounds__(256) void gemm64(const float* __restrict__ X,
                                              const float* __restrict__ W,
                                              float* __restrict__ H, int n) {
    __shared__ float sW[64][64];   // sW[k][j]
    __shared__ float sX[64][64];   // sX[r][k]; wave reads are broadcast, no conflicts
    int tid = threadIdx.x;
    int base = blockIdx.x * 64;

    for (int i = tid; i < 64 * 64; i += 256) sW[i >> 6][i & 63] = W[i];
    for (int i = tid; i < 64 * 64; i += 256) {
        int r = i >> 6, c = i & 63;
        int node = base + r;
        sX[r][c] = (node < n) ? X[node * 64 + c] : 0.0f;
    }
    __syncthreads();

    int j  = tid & 63;     // feature (lane)
    int r0 = tid >> 6;     // 0..3
    float acc[16];
#pragma unroll
    for (int ii = 0; ii < 16; ii++) acc[ii] = 0.0f;
    for (int k = 0; k < 64; k++) {
        float w = sW[k][j];
#pragma unroll
        for (int ii = 0; ii < 16; ii++)
            acc[ii] += sX[r0 + ii * 4][k] * w;
    }
#pragma unroll
    for (int ii = 0; ii < 16; ii++) {
        int node = base + r0 + ii * 4;
        if (node < n) H[node * 64 + j] = acc[ii];
    }
}

// ---------------- fused gather + epilogue ----------------
// OUT[i,:] = relu( dinv[i] * sum_{e: dst=i} H[src_e,:]*dinv[src_e]
//                  + H[i,:]*invdeg[i] + b )
__global__ __launch_bounds__(256) void gather_fused(const int* __restrict__ rowptr,
                                                    const int* __restrict__ eidx,
                                                    const float* __restrict__ dinv,
                                                    const float* __restrict__ invdeg,
                                                    const float* __restrict__ H,
                                                    const float* __restrict__ b,
                                                    float* __restrict__ OUT, int n) {
    int w = (blockIdx.x * blockDim.x + threadIdx.x) >> 6;
    int lane = threadIdx.x & 63;
    if (w >= n) return;
    int beg = rowptr[w], end = rowptr[w + 1];
    float acc = 0.f;
    int k = beg;
    for (; k + 4 <= end; k += 4) {
        int s0 = eidx[k], s1 = eidx[k + 1], s2 = eidx[k + 2], s3 = eidx[k + 3];
        float n0 = dinv[s0], n1 = dinv[s1], n2 = dinv[s2], n3 = dinv[s3];
        float h0 = H[(size_t)s0 * 64 + lane];
        float h1 = H[(size_t)s1 * 64 + lane];
        float h2 = H[(size_t)s2 * 64 + lane];
        float h3 = H[(size_t)s3 * 64 + lane];
        acc += h0 * n0 + h1 * n1 + h2 * n2 + h3 * n3;
    }
    for (; k < end; k++) {
        int s = eidx[k];
        acc += H[(size_t)s * 64 + lane] * dinv[s];
    }
    float v = acc * dinv[w] + H[(size_t)w * 64 + lane] * invdeg[w] + b[lane];
    OUT[(size_t)w * 64 + lane] = fmaxf(v, 0.f);
}

// ---------------- pooling: per-node dot with Wl, scalar atomics into graph bins ----------------
__global__ __launch_bounds__(256) void pool_dot(const float* __restrict__ H,
                                                const int* __restrict__ batch,
                                                const float* __restrict__ Wl,
                                                float* __restrict__ gsum,
                                                float* __restrict__ gcnt, int n) {
    int t = blockIdx.x * blockDim.x + threadIdx.x;
    int node = t >> 6;
    int lane = threadIdx.x & 63;
    if (node < n) {
        float v = H[(size_t)node * 64 + lane] * Wl[lane];
#pragma unroll
        for (int off = 32; off > 0; off >>= 1) v += __shfl_down(v, off);
        if (lane == 0) {
            int g = batch[node];
            atomicAdd(&gsum[g], v);
            atomicAdd(&gcnt[g], 1.0f);
        }
    }
}

__global__ void final_out(const float* __restrict__ gsum, const float* __restrict__ gcnt,
                          const float* __restrict__ bl, float* __restrict__ out) {
    int g = blockIdx.x * blockDim.x + threadIdx.x;
    if (g < N_GRAPHS) out[g] = gsum[g] / fmaxf(gcnt[g], 1.0f) + bl[0];
}

extern "C" void kernel_launch(void* const* d_in, const int* in_sizes, int n_in,
                              void* d_out, int out_size, void* d_ws, size_t ws_size,
                              hipStream_t stream) {
    const float* x     = (const float*)d_in[0];
    const int*   src   = (const int*)d_in[1];
    const int*   dst   = (const int*)d_in[2];
    const int*   batch = (const int*)d_in[3];
    const float* W1 = (const float*)d_in[4];  const float* b1 = (const float*)d_in[5];
    const float* W2 = (const float*)d_in[6];  const float* b2 = (const float*)d_in[7];
    const float* W3 = (const float*)d_in[8];  const float* b3 = (const float*)d_in[9];
    const float* Wl = (const float*)d_in[10]; const float* bl = (const float*)d_in[11];
    float* out = (float*)d_out;

    char* ws = (char*)d_ws;
    float* A      = (float*)ws;                                  // N*F
    float* B      = A + (size_t)N_NODES * F;                     // N*F
    float* dinv   = B + (size_t)N_NODES * F;                     // N
    float* invdeg = dinv + N_NODES;                              // N
    float* gsum   = invdeg + N_NODES;                            // G
    float* gcnt   = gsum + N_GRAPHS;                             // G
    int*   cnt    = (int*)(gcnt + N_GRAPHS);                     // N
    int*   rowptr = cnt + N_NODES;                               // N+1
    int*   cursor = rowptr + N_NODES + 1;                        // N
    int*   eidx   = cursor + N_NODES;                            // E

    const int GEMM_GRID     = (N_NODES + 63) / 64;               // 782
    const int EDGE_GRID     = (N_EDGES + 255) / 256;             // 3125
    const int NODEWAVE_GRID = (N_NODES * 64 + 255) / 256;        // 12500

    // ---- preprocessing: degrees + CSR-by-dst ----
    hipMemsetAsync(cnt, 0, N_NODES * sizeof(int), stream);
    hist_dst<<<EDGE_GRID, 256, 0, stream>>>(dst, cnt, N_EDGES);
    deg_finish<<<(N_NODES + 255) / 256, 256, 0, stream>>>(cnt, dinv, invdeg, N_NODES);
    scan_rowptr<<<1, SCAN_THREADS, 0, stream>>>(cnt, rowptr, cursor);
    reorder_edges<<<EDGE_GRID, 256, 0, stream>>>(src, dst, cursor, eidx, N_EDGES);

    // ---- layer 1: gemm(x->A); gather(A->B) ----
    gemm64<<<GEMM_GRID, 256, 0, stream>>>(x, W1, A, N_NODES);
    gather_fused<<<NODEWAVE_GRID, 256, 0, stream>>>(rowptr, eidx, dinv, invdeg, A, b1, B, N_NODES);

    // ---- layer 2: gemm(B->A); gather(A->B) ----
    gemm64<<<GEMM_GRID, 256, 0, stream>>>(B, W2, A, N_NODES);
    gather_fused<<<NODEWAVE_GRID, 256, 0, stream>>>(rowptr, eidx, dinv, invdeg, A, b2, B, N_NODES);

    // ---- layer 3: gemm(B->A); gather(A->B) ----
    gemm64<<<GEMM_GRID, 256, 0, stream>>>(B, W3, A, N_NODES);
    gather_fused<<<NODEWAVE_GRID, 256, 0, stream>>>(rowptr, eidx, dinv, invdeg, A, b3, B, N_NODES);

    // ---- pooling + head ----
    hipMemsetAsync(gsum, 0, 2 * N_GRAPHS * sizeof(float), stream);
    pool_dot<<<NODEWAVE_GRID, 256, 0, stream>>>(B, batch, Wl, gsum, gcnt, N_NODES);
    final_out<<<1, 256, 0, stream>>>(gsum, gcnt, bl, out);
}

// Round 3
// 481.762 us; speedup vs baseline: 1.9576x; 1.3054x over previous
//
#include <hip/hip_runtime.h>

#define N_NODES 50000
#define N_EDGES 800000
#define N_GRAPHS 256
#define F 64
#define SCAN_THREADS 1024
#define CHUNK ((N_NODES + SCAN_THREADS - 1) / SCAN_THREADS)

// ---------------- histogram of in-degrees (int) ----------------
__global__ __launch_bounds__(256) void hist_dst(const int* __restrict__ dst,
                                                int* __restrict__ cnt, int nE) {
    int e = blockIdx.x * blockDim.x + threadIdx.x;
    if (e < nE) atomicAdd(&cnt[dst[e]], 1);
}

__global__ __launch_bounds__(256) void deg_finish(const int* __restrict__ cnt,
                                                  float* __restrict__ dinv,
                                                  float* __restrict__ invdeg, int n) {
    int i = blockIdx.x * blockDim.x + threadIdx.x;
    if (i < n) {
        float d = (float)cnt[i] + 1.0f;   // self-loop
        dinv[i]   = 1.0f / sqrtf(d);
        invdeg[i] = 1.0f / d;
    }
}

// ---------------- exclusive scan -> CSR rowptr (+ cursor copy) ----------------
__global__ __launch_bounds__(SCAN_THREADS) void scan_rowptr(const int* __restrict__ cnt,
                                                            int* __restrict__ rowptr,
                                                            int* __restrict__ cursor) {
    __shared__ int ssum[SCAN_THREADS];
    int t = threadIdx.x;
    int lo = t * CHUNK;
    int hi = min(lo + CHUNK, N_NODES);
    int s = 0;
    for (int i = lo; i < hi; i++) s += cnt[i];
    ssum[t] = s;
    __syncthreads();
    for (int off = 1; off < SCAN_THREADS; off <<= 1) {
        int v = (t >= off) ? ssum[t - off] : 0;
        __syncthreads();
        ssum[t] += v;
        __syncthreads();
    }
    int run = (t > 0) ? ssum[t - 1] : 0;  // exclusive prefix of this chunk
    for (int i = lo; i < hi; i++) {
        rowptr[i] = run;
        cursor[i] = run;
        run += cnt[i];
    }
    if (t == SCAN_THREADS - 1) rowptr[N_NODES] = run;
}

// ---------------- bucket edges by dst ----------------
__global__ __launch_bounds__(256) void reorder_edges(const int* __restrict__ src,
                                                     const int* __restrict__ dst,
                                                     int* __restrict__ cursor,
                                                     int* __restrict__ eidx, int nE) {
    int e = blockIdx.x * blockDim.x + threadIdx.x;
    if (e < nE) {
        int d = dst[e];
        int pos = atomicAdd(&cursor[d], 1);
        eidx[pos] = src[e];
    }
}

// ---------------- GEMM: H[n,64] = X[n,64] @ W[64,64] ----------------
__global__ __launch_bounds__(256) void gemm64(const float* __restrict__ X,
                                              const float* __restrict__ W,
                                              float* __restrict__ H, int n) {
    __shared__ float sW[64][64];   // sW[k][j]
    __shared__ float sX[64][64];   // sX[r][k]; wave reads are broadcast, no conflicts
    int tid = threadIdx.x;
    int base = blockIdx.x * 64;

    for (int i = tid; i < 64 * 64; i += 256) sW[i >> 6][i & 63] = W[i];
    for (int i = tid; i < 64 * 64; i += 256) {
        int r = i >> 6, c = i & 63;
        int node = base + r;
        sX[r][c] = (node < n) ? X[node * 64 + c] : 0.0f;
    }
    __syncthreads();

    int j  = tid & 63;     // feature (lane)
    int r0 = tid >> 6;     // 0..3
    float acc[16];
#pragma unroll
    for (int ii = 0; ii < 16; ii++) acc[ii] = 0.0f;
    for (int k = 0; k < 64; k++) {
        float w = sW[k][j];
#pragma unroll
        for (int ii = 0; ii < 16; ii++)
            acc[ii] += sX[r0 + ii * 4][k] * w;
    }
#pragma unroll
    for (int ii = 0; ii < 16; ii++) {
        int node = base + r0 + ii * 4;
        if (node < n) H[node * 64 + j] = acc[ii];
    }
}

// ---------------- fused gather + epilogue ----------------
// OUT[i,:] = relu( dinv[i] * sum_{e: dst=i} H[src_e,:]*dinv[src_e]
//                  + H[i,:]*invdeg[i] + b )
__global__ __launch_bounds__(256) void gather_fused(const int* __restrict__ rowptr,
                                                    const int* __restrict__ eidx,
                                                    const float* __restrict__ dinv,
                                                    const float* __restrict__ invdeg,
                                                    const float* __restrict__ H,
                                                    const float* __restrict__ b,
                                                    float* __restrict__ OUT, int n) {
    int w = (blockIdx.x * blockDim.x + threadIdx.x) >> 6;
    int lane = threadIdx.x & 63;
    if (w >= n) return;
    int beg = rowptr[w], end = rowptr[w + 1];
    float acc = 0.f;
    int k = beg;
    for (; k + 4 <= end; k += 4) {
        int s0 = eidx[k], s1 = eidx[k + 1], s2 = eidx[k + 2], s3 = eidx[k + 3];
        float n0 = dinv[s0], n1 = dinv[s1], n2 = dinv[s2], n3 = dinv[s3];
        float h0 = H[(size_t)s0 * 64 + lane];
        float h1 = H[(size_t)s1 * 64 + lane];
        float h2 = H[(size_t)s2 * 64 + lane];
        float h3 = H[(size_t)s3 * 64 + lane];
        acc += h0 * n0 + h1 * n1 + h2 * n2 + h3 * n3;
    }
    for (; k < end; k++) {
        int s = eidx[k];
        acc += H[(size_t)s * 64 + lane] * dinv[s];
    }
    float v = acc * dinv[w] + H[(size_t)w * 64 + lane] * invdeg[w] + b[lane];
    OUT[(size_t)w * 64 + lane] = fmaxf(v, 0.f);
}

// ---------------- pooling: one block per graph, zero atomics ----------------
// batch is sorted, so graph g owns a contiguous node range [lo, hi).
__global__ __launch_bounds__(256) void pool_graph(const float* __restrict__ H,
                                                  const int* __restrict__ batch,
                                                  const float* __restrict__ Wl,
                                                  const float* __restrict__ bl,
                                                  float* __restrict__ out) {
    int g = blockIdx.x;
    __shared__ int slo, shi;
    __shared__ float sWl[64];
    __shared__ float wsum[4];
    int tid = threadIdx.x;
    if (tid < 64) sWl[tid] = Wl[tid];
    if (tid == 0) {
        int a = 0, b = N_NODES;
        while (a < b) { int m = (a + b) >> 1; if (batch[m] < g) a = m + 1; else b = m; }
        slo = a;
        b = N_NODES;
        while (a < b) { int m = (a + b) >> 1; if (batch[m] < g + 1) a = m + 1; else b = m; }
        shi = a;
    }
    __syncthreads();
    int lo = slo, hi = shi;
    int lane = tid & 63, wave = tid >> 6;
    float acc = 0.f;
    for (int node = lo + wave; node < hi; node += 4)
        acc += H[(size_t)node * 64 + lane] * sWl[lane];
#pragma unroll
    for (int off = 32; off > 0; off >>= 1) acc += __shfl_down(acc, off);
    if (lane == 0) wsum[wave] = acc;
    __syncthreads();
    if (tid == 0) {
        float s = wsum[0] + wsum[1] + wsum[2] + wsum[3];
        float cnt = (float)(hi - lo);
        out[g] = s / fmaxf(cnt, 1.0f) + bl[0];
    }
}

extern "C" void kernel_launch(void* const* d_in, const int* in_sizes, int n_in,
                              void* d_out, int out_size, void* d_ws, size_t ws_size,
                              hipStream_t stream) {
    const float* x     = (const float*)d_in[0];
    const int*   src   = (const int*)d_in[1];
    const int*   dst   = (const int*)d_in[2];
    const int*   batch = (const int*)d_in[3];
    const float* W1 = (const float*)d_in[4];  const float* b1 = (const float*)d_in[5];
    const float* W2 = (const float*)d_in[6];  const float* b2 = (const float*)d_in[7];
    const float* W3 = (const float*)d_in[8];  const float* b3 = (const float*)d_in[9];
    const float* Wl = (const float*)d_in[10]; const float* bl = (const float*)d_in[11];
    float* out = (float*)d_out;

    char* ws = (char*)d_ws;
    float* A      = (float*)ws;                                  // N*F
    float* B      = A + (size_t)N_NODES * F;                     // N*F
    float* dinv   = B + (size_t)N_NODES * F;                     // N
    float* invdeg = dinv + N_NODES;                              // N
    int*   cnt    = (int*)(invdeg + N_NODES);                    // N
    int*   rowptr = cnt + N_NODES;                               // N+1
    int*   cursor = rowptr + N_NODES + 1;                        // N
    int*   eidx   = cursor + N_NODES;                            // E

    const int GEMM_GRID     = (N_NODES + 63) / 64;               // 782
    const int EDGE_GRID     = (N_EDGES + 255) / 256;             // 3125
    const int NODEWAVE_GRID = (N_NODES * 64 + 255) / 256;        // 12500

    // ---- preprocessing: degrees + CSR-by-dst ----
    hipMemsetAsync(cnt, 0, N_NODES * sizeof(int), stream);
    hist_dst<<<EDGE_GRID, 256, 0, stream>>>(dst, cnt, N_EDGES);
    deg_finish<<<(N_NODES + 255) / 256, 256, 0, stream>>>(cnt, dinv, invdeg, N_NODES);
    scan_rowptr<<<1, SCAN_THREADS, 0, stream>>>(cnt, rowptr, cursor);
    reorder_edges<<<EDGE_GRID, 256, 0, stream>>>(src, dst, cursor, eidx, N_EDGES);

    // ---- layer 1: gemm(x->A); gather(A->B) ----
    gemm64<<<GEMM_GRID, 256, 0, stream>>>(x, W1, A, N_NODES);
    gather_fused<<<NODEWAVE_GRID, 256, 0, stream>>>(rowptr, eidx, dinv, invdeg, A, b1, B, N_NODES);

    // ---- layer 2: gemm(B->A); gather(A->B) ----
    gemm64<<<GEMM_GRID, 256, 0, stream>>>(B, W2, A, N_NODES);
    gather_fused<<<NODEWAVE_GRID, 256, 0, stream>>>(rowptr, eidx, dinv, invdeg, A, b2, B, N_NODES);

    // ---- layer 3: gemm(B->A); gather(A->B) ----
    gemm64<<<GEMM_GRID, 256, 0, stream>>>(B, W3, A, N_NODES);
    gather_fused<<<NODEWAVE_GRID, 256, 0, stream>>>(rowptr, eidx, dinv, invdeg, A, b3, B, N_NODES);

    // ---- pooling + head: one block per graph, no atomics ----
    pool_graph<<<N_GRAPHS, 256, 0, stream>>>(B, batch, Wl, bl, out);
}

// Round 4
// 387.664 us; speedup vs baseline: 2.4328x; 1.2427x over previous
//
#include <hip/hip_runtime.h>

#define N_NODES 50000
#define N_EDGES 800000
#define N_GRAPHS 256
#define F 64
#define NBLK ((N_NODES + 255) / 256)   // 196 scan blocks

// ---------------- histogram of in-degrees (int) ----------------
__global__ __launch_bounds__(256) void hist_dst(const int* __restrict__ dst,
                                                int* __restrict__ cnt, int nE) {
    int e = blockIdx.x * blockDim.x + threadIdx.x;
    if (e < nE) atomicAdd(&cnt[dst[e]], 1);
}

__global__ __launch_bounds__(256) void deg_finish(const int* __restrict__ cnt,
                                                  float* __restrict__ dinv,
                                                  float* __restrict__ invdeg, int n) {
    int i = blockIdx.x * blockDim.x + threadIdx.x;
    if (i < n) {
        float d = (float)cnt[i] + 1.0f;   // self-loop
        dinv[i]   = 1.0f / sqrtf(d);
        invdeg[i] = 1.0f / d;
    }
}

// ---------------- 3-phase device-wide exclusive scan -> rowptr/cursor ----------------
__global__ __launch_bounds__(256) void scan_partial_sums(const int* __restrict__ cnt,
                                                         int* __restrict__ partials) {
    __shared__ int ws[4];
    int t = threadIdx.x;
    int i = blockIdx.x * 256 + t;
    int v = (i < N_NODES) ? cnt[i] : 0;
#pragma unroll
    for (int off = 32; off > 0; off >>= 1) v += __shfl_down(v, off);
    if ((t & 63) == 0) ws[t >> 6] = v;
    __syncthreads();
    if (t == 0) partials[blockIdx.x] = ws[0] + ws[1] + ws[2] + ws[3];
}

__global__ __launch_bounds__(256) void scan_partials(int* __restrict__ partials,
                                                     int* __restrict__ rowptr) {
    __shared__ int s[256];
    int t = threadIdx.x;
    int v = (t < NBLK) ? partials[t] : 0;
    s[t] = v;
    __syncthreads();
    for (int off = 1; off < 256; off <<= 1) {
        int u = (t >= off) ? s[t - off] : 0;
        __syncthreads();
        s[t] += u;
        __syncthreads();
    }
    if (t < NBLK) partials[t] = s[t] - v;      // exclusive block offset
    if (t == 255) rowptr[N_NODES] = s[255];    // total edge count
}

__global__ __launch_bounds__(256) void scan_write(const int* __restrict__ cnt,
                                                  const int* __restrict__ partials,
                                                  int* __restrict__ rowptr,
                                                  int* __restrict__ cursor) {
    __shared__ int s[256];
    int t = threadIdx.x;
    int i = blockIdx.x * 256 + t;
    int v = (i < N_NODES) ? cnt[i] : 0;
    s[t] = v;
    __syncthreads();
    for (int off = 1; off < 256; off <<= 1) {
        int u = (t >= off) ? s[t - off] : 0;
        __syncthreads();
        s[t] += u;
        __syncthreads();
    }
    if (i < N_NODES) {
        int excl = partials[blockIdx.x] + s[t] - v;
        rowptr[i] = excl;
        cursor[i] = excl;
    }
}

// ---------------- bucket edges by dst ----------------
__global__ __launch_bounds__(256) void reorder_edges(const int* __restrict__ src,
                                                     const int* __restrict__ dst,
                                                     int* __restrict__ cursor,
                                                     int* __restrict__ eidx, int nE) {
    int e = blockIdx.x * blockDim.x + threadIdx.x;
    if (e < nE) {
        int d = dst[e];
        int pos = atomicAdd(&cursor[d], 1);
        eidx[pos] = src[e];
    }
}

// ---------------- GEMM: H[n,64] = X[n,64] @ W[64,64] ----------------
__global__ __launch_bounds__(256) void gemm64(const float* __restrict__ X,
                                              const float* __restrict__ W,
                                              float* __restrict__ H, int n) {
    __shared__ float sW[64][64];   // sW[k][j]
    __shared__ float sX[64][64];   // sX[r][k]
    int tid = threadIdx.x;
    int base = blockIdx.x * 64;

    for (int i = tid; i < 64 * 64; i += 256) sW[i >> 6][i & 63] = W[i];
    for (int i = tid; i < 64 * 64; i += 256) {
        int r = i >> 6, c = i & 63;
        int node = base + r;
        sX[r][c] = (node < n) ? X[node * 64 + c] : 0.0f;
    }
    __syncthreads();

    int j  = tid & 63;     // feature (lane)
    int r0 = tid >> 6;     // 0..3
    float acc[16];
#pragma unroll
    for (int ii = 0; ii < 16; ii++) acc[ii] = 0.0f;
    for (int k = 0; k < 64; k++) {
        float w = sW[k][j];
#pragma unroll
        for (int ii = 0; ii < 16; ii++)
            acc[ii] += sX[r0 + ii * 4][k] * w;
    }
#pragma unroll
    for (int ii = 0; ii < 16; ii++) {
        int node = base + r0 + ii * 4;
        if (node < n) H[node * 64 + j] = acc[ii];
    }
}

// ---------------- fused gather + epilogue ----------------
__global__ __launch_bounds__(256) void gather_fused(const int* __restrict__ rowptr,
                                                    const int* __restrict__ eidx,
                                                    const float* __restrict__ dinv,
                                                    const float* __restrict__ invdeg,
                                                    const float* __restrict__ H,
                                                    const float* __restrict__ b,
                                                    float* __restrict__ OUT, int n) {
    int w = (blockIdx.x * blockDim.x + threadIdx.x) >> 6;
    int lane = threadIdx.x & 63;
    if (w >= n) return;
    int beg = rowptr[w], end = rowptr[w + 1];
    float acc = 0.f;
    int k = beg;
    for (; k + 4 <= end; k += 4) {
        int s0 = eidx[k], s1 = eidx[k + 1], s2 = eidx[k + 2], s3 = eidx[k + 3];
        float n0 = dinv[s0], n1 = dinv[s1], n2 = dinv[s2], n3 = dinv[s3];
        float h0 = H[(size_t)s0 * 64 + lane];
        float h1 = H[(size_t)s1 * 64 + lane];
        float h2 = H[(size_t)s2 * 64 + lane];
        float h3 = H[(size_t)s3 * 64 + lane];
        acc += h0 * n0 + h1 * n1 + h2 * n2 + h3 * n3;
    }
    for (; k < end; k++) {
        int s = eidx[k];
        acc += H[(size_t)s * 64 + lane] * dinv[s];
    }
    float v = acc * dinv[w] + H[(size_t)w * 64 + lane] * invdeg[w] + b[lane];
    OUT[(size_t)w * 64 + lane] = fmaxf(v, 0.f);
}

// ---------------- pooling: one block per graph, zero atomics ----------------
__global__ __launch_bounds__(256) void pool_graph(const float* __restrict__ H,
                                                  const int* __restrict__ batch,
                                                  const float* __restrict__ Wl,
                                                  const float* __restrict__ bl,
                                                  float* __restrict__ out) {
    int g = blockIdx.x;
    __shared__ int slo, shi;
    __shared__ float sWl[64];
    __shared__ float wsum[4];
    int tid = threadIdx.x;
    if (tid < 64) sWl[tid] = Wl[tid];
    if (tid == 0) {
        int a = 0, b = N_NODES;
        while (a < b) { int m = (a + b) >> 1; if (batch[m] < g) a = m + 1; else b = m; }
        slo = a;
        b = N_NODES;
        while (a < b) { int m = (a + b) >> 1; if (batch[m] < g + 1) a = m + 1; else b = m; }
        shi = a;
    }
    __syncthreads();
    int lo = slo, hi = shi;
    int lane = tid & 63, wave = tid >> 6;
    float acc = 0.f;
    for (int node = lo + wave; node < hi; node += 4)
        acc += H[(size_t)node * 64 + lane] * sWl[lane];
#pragma unroll
    for (int off = 32; off > 0; off >>= 1) acc += __shfl_down(acc, off);
    if (lane == 0) wsum[wave] = acc;
    __syncthreads();
    if (tid == 0) {
        float s = wsum[0] + wsum[1] + wsum[2] + wsum[3];
        float cnt = (float)(hi - lo);
        out[g] = s / fmaxf(cnt, 1.0f) + bl[0];
    }
}

extern "C" void kernel_launch(void* const* d_in, const int* in_sizes, int n_in,
                              void* d_out, int out_size, void* d_ws, size_t ws_size,
                              hipStream_t stream) {
    const float* x     = (const float*)d_in[0];
    const int*   src   = (const int*)d_in[1];
    const int*   dst   = (const int*)d_in[2];
    const int*   batch = (const int*)d_in[3];
    const float* W1 = (const float*)d_in[4];  const float* b1 = (const float*)d_in[5];
    const float* W2 = (const float*)d_in[6];  const float* b2 = (const float*)d_in[7];
    const float* W3 = (const float*)d_in[8];  const float* b3 = (const float*)d_in[9];
    const float* Wl = (const float*)d_in[10]; const float* bl = (const float*)d_in[11];
    float* out = (float*)d_out;

    char* ws = (char*)d_ws;
    float* A       = (float*)ws;                                 // N*F
    float* B       = A + (size_t)N_NODES * F;                    // N*F
    float* dinv    = B + (size_t)N_NODES * F;                    // N
    float* invdeg  = dinv + N_NODES;                             // N
    int*   cnt     = (int*)(invdeg + N_NODES);                   // N
    int*   rowptr  = cnt + N_NODES;                              // N+1
    int*   cursor  = rowptr + N_NODES + 1;                       // N
    int*   parts   = cursor + N_NODES;                           // NBLK
    int*   eidx    = parts + NBLK;                               // E

    const int GEMM_GRID     = (N_NODES + 63) / 64;               // 782
    const int EDGE_GRID     = (N_EDGES + 255) / 256;             // 3125
    const int NODEWAVE_GRID = (N_NODES * 64 + 255) / 256;        // 12500

    // ---- preprocessing: degrees + CSR-by-dst ----
    hipMemsetAsync(cnt, 0, N_NODES * sizeof(int), stream);
    hist_dst<<<EDGE_GRID, 256, 0, stream>>>(dst, cnt, N_EDGES);
    deg_finish<<<(N_NODES + 255) / 256, 256, 0, stream>>>(cnt, dinv, invdeg, N_NODES);
    scan_partial_sums<<<NBLK, 256, 0, stream>>>(cnt, parts);
    scan_partials<<<1, 256, 0, stream>>>(parts, rowptr);
    scan_write<<<NBLK, 256, 0, stream>>>(cnt, parts, rowptr, cursor);
    reorder_edges<<<EDGE_GRID, 256, 0, stream>>>(src, dst, cursor, eidx, N_EDGES);

    // ---- layer 1: gemm(x->A); gather(A->B) ----
    gemm64<<<GEMM_GRID, 256, 0, stream>>>(x, W1, A, N_NODES);
    gather_fused<<<NODEWAVE_GRID, 256, 0, stream>>>(rowptr, eidx, dinv, invdeg, A, b1, B, N_NODES);

    // ---- layer 2: gemm(B->A); gather(A->B) ----
    gemm64<<<GEMM_GRID, 256, 0, stream>>>(B, W2, A, N_NODES);
    gather_fused<<<NODEWAVE_GRID, 256, 0, stream>>>(rowptr, eidx, dinv, invdeg, A, b2, B, N_NODES);

    // ---- layer 3: gemm(B->A); gather(A->B) ----
    gemm64<<<GEMM_GRID, 256, 0, stream>>>(B, W3, A, N_NODES);
    gather_fused<<<NODEWAVE_GRID, 256, 0, stream>>>(rowptr, eidx, dinv, invdeg, A, b3, B, N_NODES);

    // ---- pooling + head ----
    pool_graph<<<N_GRAPHS, 256, 0, stream>>>(B, batch, Wl, bl, out);
}

// Round 5
// 313.369 us; speedup vs baseline: 3.0096x; 1.2371x over previous
//
#include <hip/hip_runtime.h>

#define N_NODES 50000
#define N_EDGES 800000
#define N_GRAPHS 256
#define F 64
#define NBLK ((N_NODES + 255) / 256)   // 196 scan blocks

// ---------------- histogram of in-degrees; also records each edge's rank ----------------
__global__ __launch_bounds__(256) void hist_dst(const int* __restrict__ dst,
                                                int* __restrict__ cnt,
                                                int* __restrict__ rank, int nE) {
    int e = blockIdx.x * blockDim.x + threadIdx.x;
    if (e < nE) rank[e] = atomicAdd(&cnt[dst[e]], 1);
}

__global__ __launch_bounds__(256) void deg_finish(const int* __restrict__ cnt,
                                                  float* __restrict__ dinv,
                                                  float* __restrict__ invdeg, int n) {
    int i = blockIdx.x * blockDim.x + threadIdx.x;
    if (i < n) {
        float d = (float)cnt[i] + 1.0f;   // self-loop
        dinv[i]   = 1.0f / sqrtf(d);
        invdeg[i] = 1.0f / d;
    }
}

// ---------------- 3-phase device-wide exclusive scan -> rowptr ----------------
__global__ __launch_bounds__(256) void scan_partial_sums(const int* __restrict__ cnt,
                                                         int* __restrict__ partials) {
    __shared__ int ws[4];
    int t = threadIdx.x;
    int i = blockIdx.x * 256 + t;
    int v = (i < N_NODES) ? cnt[i] : 0;
#pragma unroll
    for (int off = 32; off > 0; off >>= 1) v += __shfl_down(v, off);
    if ((t & 63) == 0) ws[t >> 6] = v;
    __syncthreads();
    if (t == 0) partials[blockIdx.x] = ws[0] + ws[1] + ws[2] + ws[3];
}

__global__ __launch_bounds__(256) void scan_partials(int* __restrict__ partials,
                                                     int* __restrict__ rowptr) {
    __shared__ int s[256];
    int t = threadIdx.x;
    int v = (t < NBLK) ? partials[t] : 0;
    s[t] = v;
    __syncthreads();
    for (int off = 1; off < 256; off <<= 1) {
        int u = (t >= off) ? s[t - off] : 0;
        __syncthreads();
        s[t] += u;
        __syncthreads();
    }
    if (t < NBLK) partials[t] = s[t] - v;      // exclusive block offset
    if (t == 255) rowptr[N_NODES] = s[255];    // total edge count
}

__global__ __launch_bounds__(256) void scan_write(const int* __restrict__ cnt,
                                                  const int* __restrict__ partials,
                                                  int* __restrict__ rowptr) {
    __shared__ int s[256];
    int t = threadIdx.x;
    int i = blockIdx.x * 256 + t;
    int v = (i < N_NODES) ? cnt[i] : 0;
    s[t] = v;
    __syncthreads();
    for (int off = 1; off < 256; off <<= 1) {
        int u = (t >= off) ? s[t - off] : 0;
        __syncthreads();
        s[t] += u;
        __syncthreads();
    }
    if (i < N_NODES) rowptr[i] = partials[blockIdx.x] + s[t] - v;
}

// ---------------- bucket edges by dst (no atomics: pos = rowptr[d] + rank[e]) ----------------
__global__ __launch_bounds__(256) void reorder_edges(const int* __restrict__ src,
                                                     const int* __restrict__ dst,
                                                     const int* __restrict__ rowptr,
                                                     const int* __restrict__ rank,
                                                     int* __restrict__ eidx, int nE) {
    int e = blockIdx.x * blockDim.x + threadIdx.x;
    if (e < nE) {
        int pos = rowptr[dst[e]] + rank[e];
        eidx[pos] = src[e];
    }
}

// ---------------- GEMM: H[n,64] = X[n,64] @ W[64,64], float4 pipeline ----------------
// 128-node tile / block; thread t: feature quad fg = t&15, node subgroup ng = t>>4.
// Thread computes 8 nodes (ng + 16*ii) x 4 features.
#define XSTRIDE 17   // float4 stride pad: ng groups land on distinct banks
__global__ __launch_bounds__(256) void gemm64_v(const float* __restrict__ X,
                                                const float* __restrict__ W,
                                                float* __restrict__ H, int n) {
    __shared__ float4 sW[64 * 16];        // sW[k*16 + fg] = W[k][4fg..4fg+3]
    __shared__ float4 sX[128 * XSTRIDE];  // sX[r*17 + kg] = X[base+r][4kg..4kg+3]
    int tid = threadIdx.x;
    int base = blockIdx.x * 128;

    const float4* W4 = (const float4*)W;
    for (int i = tid; i < 64 * 16; i += 256) sW[i] = W4[i];
    const float4* X4 = (const float4*)X;
    for (int i = tid; i < 128 * 16; i += 256) {
        int r = i >> 4, kg = i & 15;
        int node = base + r;
        sX[r * XSTRIDE + kg] = (node < n) ? X4[(size_t)node * 16 + kg]
                                          : make_float4(0.f, 0.f, 0.f, 0.f);
    }
    __syncthreads();

    int fg = tid & 15;
    int ng = tid >> 4;
    float4 acc[8];
#pragma unroll
    for (int ii = 0; ii < 8; ii++) acc[ii] = make_float4(0.f, 0.f, 0.f, 0.f);

    for (int kg = 0; kg < 16; kg++) {
        float4 xv[8];
#pragma unroll
        for (int ii = 0; ii < 8; ii++) xv[ii] = sX[(ng + 16 * ii) * XSTRIDE + kg];
#pragma unroll
        for (int kk = 0; kk < 4; kk++) {
            float4 wv = sW[(4 * kg + kk) * 16 + fg];
#pragma unroll
            for (int ii = 0; ii < 8; ii++) {
                float xs = (kk == 0) ? xv[ii].x : (kk == 1) ? xv[ii].y
                         : (kk == 2) ? xv[ii].z : xv[ii].w;
                acc[ii].x += wv.x * xs;
                acc[ii].y += wv.y * xs;
                acc[ii].z += wv.z * xs;
                acc[ii].w += wv.w * xs;
            }
        }
    }

    float4* H4 = (float4*)H;
#pragma unroll
    for (int ii = 0; ii < 8; ii++) {
        int node = base + ng + 16 * ii;
        if (node < n) H4[(size_t)node * 16 + fg] = acc[ii];
    }
}

// ---------------- fused gather + epilogue, 4 edges/wave x float4 ----------------
// OUT[i,:] = relu( dinv[i]*sum_{e:dst=i} H[src_e,:]*dinv[src_e] + H[i,:]*invdeg[i] + b )
__global__ __launch_bounds__(256) void gather_fused(const int* __restrict__ rowptr,
                                                    const int* __restrict__ eidx,
                                                    const float* __restrict__ dinv,
                                                    const float* __restrict__ invdeg,
                                                    const float* __restrict__ H,
                                                    const float* __restrict__ b,
                                                    float* __restrict__ OUT, int n) {
    int w = (blockIdx.x * blockDim.x + threadIdx.x) >> 6;
    int lane = threadIdx.x & 63;
    if (w >= n) return;
    int g = lane >> 4;      // edge subgroup 0..3
    int f = lane & 15;      // feature quad
    int beg = rowptr[w], end = rowptr[w + 1];
    const float4* H4 = (const float4*)H;

    float ax = 0.f, ay = 0.f, az = 0.f, aw = 0.f;
    for (int k = beg + g; k < end; k += 4) {
        int s = eidx[k];
        float nm = dinv[s];
        float4 h = H4[(size_t)s * 16 + f];
        ax += h.x * nm; ay += h.y * nm; az += h.z * nm; aw += h.w * nm;
    }
    // reduce across the 4 edge subgroups (lanes xor 16, 32)
    ax += __shfl_xor(ax, 16); ax += __shfl_xor(ax, 32);
    ay += __shfl_xor(ay, 16); ay += __shfl_xor(ay, 32);
    az += __shfl_xor(az, 16); az += __shfl_xor(az, 32);
    aw += __shfl_xor(aw, 16); aw += __shfl_xor(aw, 32);

    if (g == 0) {
        float di = dinv[w], iv = invdeg[w];
        float4 h  = H4[(size_t)w * 16 + f];
        float4 bb = ((const float4*)b)[f];
        float4 o;
        o.x = fmaxf(ax * di + h.x * iv + bb.x, 0.f);
        o.y = fmaxf(ay * di + h.y * iv + bb.y, 0.f);
        o.z = fmaxf(az * di + h.z * iv + bb.z, 0.f);
        o.w = fmaxf(aw * di + h.w * iv + bb.w, 0.f);
        ((float4*)OUT)[(size_t)w * 16 + f] = o;
    }
}

// ---------------- pooling: one block per graph, zero atomics ----------------
__global__ __launch_bounds__(256) void pool_graph(const float* __restrict__ H,
                                                  const int* __restrict__ batch,
                                                  const float* __restrict__ Wl,
                                                  const float* __restrict__ bl,
                                                  float* __restrict__ out) {
    int g = blockIdx.x;
    __shared__ int slo, shi;
    __shared__ float sWl[64];
    __shared__ float wsum[4];
    int tid = threadIdx.x;
    if (tid < 64) sWl[tid] = Wl[tid];
    if (tid == 0) {
        int a = 0, b = N_NODES;
        while (a < b) { int m = (a + b) >> 1; if (batch[m] < g) a = m + 1; else b = m; }
        slo = a;
        b = N_NODES;
        while (a < b) { int m = (a + b) >> 1; if (batch[m] < g + 1) a = m + 1; else b = m; }
        shi = a;
    }
    __syncthreads();
    int lo = slo, hi = shi;
    int lane = tid & 63, wave = tid >> 6;
    float acc = 0.f;
    for (int node = lo + wave; node < hi; node += 4)
        acc += H[(size_t)node * 64 + lane] * sWl[lane];
#pragma unroll
    for (int off = 32; off > 0; off >>= 1) acc += __shfl_down(acc, off);
    if (lane == 0) wsum[wave] = acc;
    __syncthreads();
    if (tid == 0) {
        float s = wsum[0] + wsum[1] + wsum[2] + wsum[3];
        float cnt = (float)(hi - lo);
        out[g] = s / fmaxf(cnt, 1.0f) + bl[0];
    }
}

extern "C" void kernel_launch(void* const* d_in, const int* in_sizes, int n_in,
                              void* d_out, int out_size, void* d_ws, size_t ws_size,
                              hipStream_t stream) {
    const float* x     = (const float*)d_in[0];
    const int*   src   = (const int*)d_in[1];
    const int*   dst   = (const int*)d_in[2];
    const int*   batch = (const int*)d_in[3];
    const float* W1 = (const float*)d_in[4];  const float* b1 = (const float*)d_in[5];
    const float* W2 = (const float*)d_in[6];  const float* b2 = (const float*)d_in[7];
    const float* W3 = (const float*)d_in[8];  const float* b3 = (const float*)d_in[9];
    const float* Wl = (const float*)d_in[10]; const float* bl = (const float*)d_in[11];
    float* out = (float*)d_out;

    char* ws = (char*)d_ws;
    float* A       = (float*)ws;                                 // N*F
    float* B       = A + (size_t)N_NODES * F;                    // N*F
    float* dinv    = B + (size_t)N_NODES * F;                    // N
    float* invdeg  = dinv + N_NODES;                             // N
    int*   cnt     = (int*)(invdeg + N_NODES);                   // N
    int*   rowptr  = cnt + N_NODES;                              // N+1
    int*   parts   = rowptr + N_NODES + 1;                       // NBLK
    int*   rank    = parts + NBLK;                               // E
    int*   eidx    = rank + N_EDGES;                             // E

    const int GEMM_GRID     = (N_NODES + 127) / 128;             // 391
    const int EDGE_GRID     = (N_EDGES + 255) / 256;             // 3125
    const int NODEWAVE_GRID = (N_NODES * 64 + 255) / 256;        // 12500

    // ---- preprocessing: degrees + ranks + CSR-by-dst ----
    hipMemsetAsync(cnt, 0, N_NODES * sizeof(int), stream);
    hist_dst<<<EDGE_GRID, 256, 0, stream>>>(dst, cnt, rank, N_EDGES);
    deg_finish<<<(N_NODES + 255) / 256, 256, 0, stream>>>(cnt, dinv, invdeg, N_NODES);
    scan_partial_sums<<<NBLK, 256, 0, stream>>>(cnt, parts);
    scan_partials<<<1, 256, 0, stream>>>(parts, rowptr);
    scan_write<<<NBLK, 256, 0, stream>>>(cnt, parts, rowptr);
    reorder_edges<<<EDGE_GRID, 256, 0, stream>>>(src, dst, rowptr, rank, eidx, N_EDGES);

    // ---- layer 1: gemm(x->A); gather(A->B) ----
    gemm64_v<<<GEMM_GRID, 256, 0, stream>>>(x, W1, A, N_NODES);
    gather_fused<<<NODEWAVE_GRID, 256, 0, stream>>>(rowptr, eidx, dinv, invdeg, A, b1, B, N_NODES);

    // ---- layer 2: gemm(B->A); gather(A->B) ----
    gemm64_v<<<GEMM_GRID, 256, 0, stream>>>(B, W2, A, N_NODES);
    gather_fused<<<NODEWAVE_GRID, 256, 0, stream>>>(rowptr, eidx, dinv, invdeg, A, b2, B, N_NODES);

    // ---- layer 3: gemm(B->A); gather(A->B) ----
    gemm64_v<<<GEMM_GRID, 256, 0, stream>>>(B, W3, A, N_NODES);
    gather_fused<<<NODEWAVE_GRID, 256, 0, stream>>>(rowptr, eidx, dinv, invdeg, A, b3, B, N_NODES);

    // ---- pooling + head ----
    pool_graph<<<N_GRAPHS, 256, 0, stream>>>(B, batch, Wl, bl, out);
}

// Round 6
// 304.207 us; speedup vs baseline: 3.1002x; 1.0301x over previous
//
#include <hip/hip_runtime.h>

#define N_NODES 50000
#define N_EDGES 800000
#define N_GRAPHS 256
#define F 64
#define NBLK ((N_NODES + 255) / 256)   // 196 scan blocks

// ---------------- histogram of in-degrees; also records each edge's rank ----------------
__global__ __launch_bounds__(256) void hist_dst(const int* __restrict__ dst,
                                                int* __restrict__ cnt,
                                                int* __restrict__ rank, int nE) {
    int e = blockIdx.x * blockDim.x + threadIdx.x;
    if (e < nE) rank[e] = atomicAdd(&cnt[dst[e]], 1);
}

__global__ __launch_bounds__(256) void deg_finish(const int* __restrict__ cnt,
                                                  float* __restrict__ dinv, int n) {
    int i = blockIdx.x * blockDim.x + threadIdx.x;
    if (i < n) {
        float d = (float)cnt[i] + 1.0f;   // self-loop
        dinv[i] = 1.0f / sqrtf(d);
    }
}

// ---------------- 3-phase device-wide exclusive scan -> rowptr ----------------
__global__ __launch_bounds__(256) void scan_partial_sums(const int* __restrict__ cnt,
                                                         int* __restrict__ partials) {
    __shared__ int ws[4];
    int t = threadIdx.x;
    int i = blockIdx.x * 256 + t;
    int v = (i < N_NODES) ? cnt[i] : 0;
#pragma unroll
    for (int off = 32; off > 0; off >>= 1) v += __shfl_down(v, off);
    if ((t & 63) == 0) ws[t >> 6] = v;
    __syncthreads();
    if (t == 0) partials[blockIdx.x] = ws[0] + ws[1] + ws[2] + ws[3];
}

__global__ __launch_bounds__(256) void scan_partials(int* __restrict__ partials,
                                                     int* __restrict__ rowptr) {
    __shared__ int s[256];
    int t = threadIdx.x;
    int v = (t < NBLK) ? partials[t] : 0;
    s[t] = v;
    __syncthreads();
    for (int off = 1; off < 256; off <<= 1) {
        int u = (t >= off) ? s[t - off] : 0;
        __syncthreads();
        s[t] += u;
        __syncthreads();
    }
    if (t < NBLK) partials[t] = s[t] - v;      // exclusive block offset
    if (t == 255) rowptr[N_NODES] = s[255];    // total edge count
}

__global__ __launch_bounds__(256) void scan_write(const int* __restrict__ cnt,
                                                  const int* __restrict__ partials,
                                                  int* __restrict__ rowptr) {
    __shared__ int s[256];
    int t = threadIdx.x;
    int i = blockIdx.x * 256 + t;
    int v = (i < N_NODES) ? cnt[i] : 0;
    s[t] = v;
    __syncthreads();
    for (int off = 1; off < 256; off <<= 1) {
        int u = (t >= off) ? s[t - off] : 0;
        __syncthreads();
        s[t] += u;
        __syncthreads();
    }
    if (i < N_NODES) rowptr[i] = partials[blockIdx.x] + s[t] - v;
}

// ---------------- bucket edges by dst (no atomics: pos = rowptr[d] + rank[e]) ----------------
__global__ __launch_bounds__(256) void reorder_edges(const int* __restrict__ src,
                                                     const int* __restrict__ dst,
                                                     const int* __restrict__ rowptr,
                                                     const int* __restrict__ rank,
                                                     int* __restrict__ eidx, int nE) {
    int e = blockIdx.x * blockDim.x + threadIdx.x;
    if (e < nE) {
        int pos = rowptr[dst[e]] + rank[e];
        eidx[pos] = src[e];
    }
}

// ---------------- GEMM + dinv fold: Hn[i,:] = (X[i,:] @ W) * dinv[i] ----------------
// 128-node tile / block; thread t: feature quad fg = t&15, node subgroup ng = t>>4.
#define XSTRIDE 17   // float4 stride pad
__global__ __launch_bounds__(256) void gemm64_v(const float* __restrict__ X,
                                                const float* __restrict__ W,
                                                const float* __restrict__ dinv,
                                                float* __restrict__ Hn, int n) {
    __shared__ float4 sW[64 * 16];        // sW[k*16 + fg] = W[k][4fg..4fg+3]
    __shared__ float4 sX[128 * XSTRIDE];  // sX[r*17 + kg] = X[base+r][4kg..4kg+3]
    int tid = threadIdx.x;
    int base = blockIdx.x * 128;

    const float4* W4 = (const float4*)W;
    for (int i = tid; i < 64 * 16; i += 256) sW[i] = W4[i];
    const float4* X4 = (const float4*)X;
    for (int i = tid; i < 128 * 16; i += 256) {
        int r = i >> 4, kg = i & 15;
        int node = base + r;
        sX[r * XSTRIDE + kg] = (node < n) ? X4[(size_t)node * 16 + kg]
                                          : make_float4(0.f, 0.f, 0.f, 0.f);
    }
    __syncthreads();

    int fg = tid & 15;
    int ng = tid >> 4;
    float4 acc[8];
#pragma unroll
    for (int ii = 0; ii < 8; ii++) acc[ii] = make_float4(0.f, 0.f, 0.f, 0.f);

    for (int kg = 0; kg < 16; kg++) {
        float4 xv[8];
#pragma unroll
        for (int ii = 0; ii < 8; ii++) xv[ii] = sX[(ng + 16 * ii) * XSTRIDE + kg];
#pragma unroll
        for (int kk = 0; kk < 4; kk++) {
            float4 wv = sW[(4 * kg + kk) * 16 + fg];
#pragma unroll
            for (int ii = 0; ii < 8; ii++) {
                float xs = (kk == 0) ? xv[ii].x : (kk == 1) ? xv[ii].y
                         : (kk == 2) ? xv[ii].z : xv[ii].w;
                acc[ii].x += wv.x * xs;
                acc[ii].y += wv.y * xs;
                acc[ii].z += wv.z * xs;
                acc[ii].w += wv.w * xs;
            }
        }
    }

    float4* H4 = (float4*)Hn;
#pragma unroll
    for (int ii = 0; ii < 8; ii++) {
        int node = base + ng + 16 * ii;
        if (node < n) {
            float d = dinv[node];
            float4 o = acc[ii];
            o.x *= d; o.y *= d; o.z *= d; o.w *= d;
            H4[(size_t)node * 16 + fg] = o;
        }
    }
}

// ---------------- fused gather + epilogue: pure row gather ----------------
// OUT[i,:] = relu( dinv[i] * ( sum_{e:dst=i} Hn[src_e,:] + Hn[i,:] ) + b )
// wave per node; lane = g*8+f: 8 edge subgroups x 8 feature lanes x 32 B.
__global__ __launch_bounds__(256) void gather_fused(const int* __restrict__ rowptr,
                                                    const int* __restrict__ eidx,
                                                    const float* __restrict__ dinv,
                                                    const float* __restrict__ Hn,
                                                    const float* __restrict__ b,
                                                    float* __restrict__ OUT, int n) {
    int w = (blockIdx.x * blockDim.x + threadIdx.x) >> 6;
    int lane = threadIdx.x & 63;
    if (w >= n) return;
    int g = lane >> 3;      // edge subgroup 0..7
    int f = lane & 7;       // feature quad (covers quads f and f+8)
    int beg = rowptr[w], end = rowptr[w + 1];
    const float4* H4 = (const float4*)Hn;

    float4 a0 = make_float4(0.f, 0.f, 0.f, 0.f);
    float4 a1 = make_float4(0.f, 0.f, 0.f, 0.f);
    for (int k = beg + g; k < end; k += 8) {
        int s = eidx[k];
        float4 h0 = H4[(size_t)s * 16 + f];
        float4 h1 = H4[(size_t)s * 16 + 8 + f];
        a0.x += h0.x; a0.y += h0.y; a0.z += h0.z; a0.w += h0.w;
        a1.x += h1.x; a1.y += h1.y; a1.z += h1.z; a1.w += h1.w;
    }
    // reduce across the 8 edge subgroups (lanes xor 8, 16, 32)
#pragma unroll
    for (int m = 8; m <= 32; m <<= 1) {
        a0.x += __shfl_xor(a0.x, m); a0.y += __shfl_xor(a0.y, m);
        a0.z += __shfl_xor(a0.z, m); a0.w += __shfl_xor(a0.w, m);
        a1.x += __shfl_xor(a1.x, m); a1.y += __shfl_xor(a1.y, m);
        a1.z += __shfl_xor(a1.z, m); a1.w += __shfl_xor(a1.w, m);
    }

    if (g == 0) {
        float di = dinv[w];
        float4 h0 = H4[(size_t)w * 16 + f];
        float4 h1 = H4[(size_t)w * 16 + 8 + f];
        float4 b0 = ((const float4*)b)[f];
        float4 b1 = ((const float4*)b)[8 + f];
        float4 o0, o1;
        o0.x = fmaxf(di * (a0.x + h0.x) + b0.x, 0.f);
        o0.y = fmaxf(di * (a0.y + h0.y) + b0.y, 0.f);
        o0.z = fmaxf(di * (a0.z + h0.z) + b0.z, 0.f);
        o0.w = fmaxf(di * (a0.w + h0.w) + b0.w, 0.f);
        o1.x = fmaxf(di * (a1.x + h1.x) + b1.x, 0.f);
        o1.y = fmaxf(di * (a1.y + h1.y) + b1.y, 0.f);
        o1.z = fmaxf(di * (a1.z + h1.z) + b1.z, 0.f);
        o1.w = fmaxf(di * (a1.w + h1.w) + b1.w, 0.f);
        ((float4*)OUT)[(size_t)w * 16 + f]     = o0;
        ((float4*)OUT)[(size_t)w * 16 + 8 + f] = o1;
    }
}

// ---------------- pooling: one block per graph, zero atomics ----------------
__global__ __launch_bounds__(256) void pool_graph(const float* __restrict__ H,
                                                  const int* __restrict__ batch,
                                                  const float* __restrict__ Wl,
                                                  const float* __restrict__ bl,
                                                  float* __restrict__ out) {
    int g = blockIdx.x;
    __shared__ int slo, shi;
    __shared__ float sWl[64];
    __shared__ float wsum[4];
    int tid = threadIdx.x;
    if (tid < 64) sWl[tid] = Wl[tid];
    if (tid == 0) {
        int a = 0, b = N_NODES;
        while (a < b) { int m = (a + b) >> 1; if (batch[m] < g) a = m + 1; else b = m; }
        slo = a;
        b = N_NODES;
        while (a < b) { int m = (a + b) >> 1; if (batch[m] < g + 1) a = m + 1; else b = m; }
        shi = a;
    }
    __syncthreads();
    int lo = slo, hi = shi;
    int lane = tid & 63, wave = tid >> 6;
    float acc = 0.f;
    for (int node = lo + wave; node < hi; node += 4)
        acc += H[(size_t)node * 64 + lane] * sWl[lane];
#pragma unroll
    for (int off = 32; off > 0; off >>= 1) acc += __shfl_down(acc, off);
    if (lane == 0) wsum[wave] = acc;
    __syncthreads();
    if (tid == 0) {
        float s = wsum[0] + wsum[1] + wsum[2] + wsum[3];
        float cnt = (float)(hi - lo);
        out[g] = s / fmaxf(cnt, 1.0f) + bl[0];
    }
}

extern "C" void kernel_launch(void* const* d_in, const int* in_sizes, int n_in,
                              void* d_out, int out_size, void* d_ws, size_t ws_size,
                              hipStream_t stream) {
    const float* x     = (const float*)d_in[0];
    const int*   src   = (const int*)d_in[1];
    const int*   dst   = (const int*)d_in[2];
    const int*   batch = (const int*)d_in[3];
    const float* W1 = (const float*)d_in[4];  const float* b1 = (const float*)d_in[5];
    const float* W2 = (const float*)d_in[6];  const float* b2 = (const float*)d_in[7];
    const float* W3 = (const float*)d_in[8];  const float* b3 = (const float*)d_in[9];
    const float* Wl = (const float*)d_in[10]; const float* bl = (const float*)d_in[11];
    float* out = (float*)d_out;

    char* ws = (char*)d_ws;
    float* A       = (float*)ws;                                 // N*F
    float* B       = A + (size_t)N_NODES * F;                    // N*F
    float* dinv    = B + (size_t)N_NODES * F;                    // N
    int*   cnt     = (int*)(dinv + N_NODES);                     // N
    int*   rowptr  = cnt + N_NODES;                              // N+1
    int*   parts   = rowptr + N_NODES + 1;                       // NBLK
    int*   rank    = parts + NBLK;                               // E
    int*   eidx    = rank + N_EDGES;                             // E

    const int GEMM_GRID     = (N_NODES + 127) / 128;             // 391
    const int EDGE_GRID     = (N_EDGES + 255) / 256;             // 3125
    const int NODEWAVE_GRID = (N_NODES * 64 + 255) / 256;        // 12500

    // ---- preprocessing: degrees + ranks + CSR-by-dst ----
    hipMemsetAsync(cnt, 0, N_NODES * sizeof(int), stream);
    hist_dst<<<EDGE_GRID, 256, 0, stream>>>(dst, cnt, rank, N_EDGES);
    deg_finish<<<(N_NODES + 255) / 256, 256, 0, stream>>>(cnt, dinv, N_NODES);
    scan_partial_sums<<<NBLK, 256, 0, stream>>>(cnt, parts);
    scan_partials<<<1, 256, 0, stream>>>(parts, rowptr);
    scan_write<<<NBLK, 256, 0, stream>>>(cnt, parts, rowptr);
    reorder_edges<<<EDGE_GRID, 256, 0, stream>>>(src, dst, rowptr, rank, eidx, N_EDGES);

    // ---- layer 1: gemm(x->A, *dinv); gather(A->B) ----
    gemm64_v<<<GEMM_GRID, 256, 0, stream>>>(x, W1, dinv, A, N_NODES);
    gather_fused<<<NODEWAVE_GRID, 256, 0, stream>>>(rowptr, eidx, dinv, A, b1, B, N_NODES);

    // ---- layer 2 ----
    gemm64_v<<<GEMM_GRID, 256, 0, stream>>>(B, W2, dinv, A, N_NODES);
    gather_fused<<<NODEWAVE_GRID, 256, 0, stream>>>(rowptr, eidx, dinv, A, b2, B, N_NODES);

    // ---- layer 3 ----
    gemm64_v<<<GEMM_GRID, 256, 0, stream>>>(B, W3, dinv, A, N_NODES);
    gather_fused<<<NODEWAVE_GRID, 256, 0, stream>>>(rowptr, eidx, dinv, A, b3, B, N_NODES);

    // ---- pooling + head ----
    pool_graph<<<N_GRAPHS, 256, 0, stream>>>(B, batch, Wl, bl, out);
}

// Round 7
// 301.055 us; speedup vs baseline: 3.1327x; 1.0105x over previous
//
#include <hip/hip_runtime.h>

#define N_NODES 50000
#define N_EDGES 800000
#define N_GRAPHS 256
#define F 64
#define NBLK ((N_NODES + 255) / 256)   // 196 scan blocks

// ---------------- histogram of in-degrees; also records each edge's rank ----------------
__global__ __launch_bounds__(256) void hist_dst(const int* __restrict__ dst,
                                                int* __restrict__ cnt,
                                                int* __restrict__ rank, int nE) {
    int e = blockIdx.x * blockDim.x + threadIdx.x;
    if (e < nE) rank[e] = atomicAdd(&cnt[dst[e]], 1);
}

// ---------------- 3-phase device-wide exclusive scan -> rowptr (+dinv fused) ----------------
__global__ __launch_bounds__(256) void scan_partial_sums(const int* __restrict__ cnt,
                                                         int* __restrict__ partials) {
    __shared__ int ws[4];
    int t = threadIdx.x;
    int i = blockIdx.x * 256 + t;
    int v = (i < N_NODES) ? cnt[i] : 0;
#pragma unroll
    for (int off = 32; off > 0; off >>= 1) v += __shfl_down(v, off);
    if ((t & 63) == 0) ws[t >> 6] = v;
    __syncthreads();
    if (t == 0) partials[blockIdx.x] = ws[0] + ws[1] + ws[2] + ws[3];
}

__global__ __launch_bounds__(256) void scan_partials(int* __restrict__ partials,
                                                     int* __restrict__ rowptr) {
    __shared__ int s[256];
    int t = threadIdx.x;
    int v = (t < NBLK) ? partials[t] : 0;
    s[t] = v;
    __syncthreads();
    for (int off = 1; off < 256; off <<= 1) {
        int u = (t >= off) ? s[t - off] : 0;
        __syncthreads();
        s[t] += u;
        __syncthreads();
    }
    if (t < NBLK) partials[t] = s[t] - v;      // exclusive block offset
    if (t == 255) rowptr[N_NODES] = s[255];    // total edge count
}

__global__ __launch_bounds__(256) void scan_write(const int* __restrict__ cnt,
                                                  const int* __restrict__ partials,
                                                  int* __restrict__ rowptr,
                                                  float* __restrict__ dinv) {
    __shared__ int s[256];
    int t = threadIdx.x;
    int i = blockIdx.x * 256 + t;
    int v = (i < N_NODES) ? cnt[i] : 0;
    s[t] = v;
    __syncthreads();
    for (int off = 1; off < 256; off <<= 1) {
        int u = (t >= off) ? s[t - off] : 0;
        __syncthreads();
        s[t] += u;
        __syncthreads();
    }
    if (i < N_NODES) {
        rowptr[i] = partials[blockIdx.x] + s[t] - v;
        dinv[i] = 1.0f / sqrtf((float)v + 1.0f);   // self-loop degree
    }
}

// ---------------- bucket edges by dst; store BYTE OFFSET of source row ----------------
__global__ __launch_bounds__(256) void reorder_edges(const int* __restrict__ src,
                                                     const int* __restrict__ dst,
                                                     const int* __restrict__ rowptr,
                                                     const int* __restrict__ rank,
                                                     int* __restrict__ eidx, int nE) {
    int e = blockIdx.x * blockDim.x + threadIdx.x;
    if (e < nE) {
        int pos = rowptr[dst[e]] + rank[e];
        eidx[pos] = src[e] << 8;   // row byte offset (256 B/row)
    }
}

// ---------------- GEMM + dinv fold: Hn[i,:] = (X[i,:] @ W) * dinv[i] ----------------
#define XSTRIDE 17   // float4 stride pad
__global__ __launch_bounds__(256) void gemm64_v(const float* __restrict__ X,
                                                const float* __restrict__ W,
                                                const float* __restrict__ dinv,
                                                float* __restrict__ Hn, int n) {
    __shared__ float4 sW[64 * 16];        // sW[k*16 + fg] = W[k][4fg..4fg+3]
    __shared__ float4 sX[128 * XSTRIDE];  // sX[r*17 + kg] = X[base+r][4kg..4kg+3]
    int tid = threadIdx.x;
    int base = blockIdx.x * 128;

    const float4* W4 = (const float4*)W;
    for (int i = tid; i < 64 * 16; i += 256) sW[i] = W4[i];
    const float4* X4 = (const float4*)X;
    for (int i = tid; i < 128 * 16; i += 256) {
        int r = i >> 4, kg = i & 15;
        int node = base + r;
        sX[r * XSTRIDE + kg] = (node < n) ? X4[(size_t)node * 16 + kg]
                                          : make_float4(0.f, 0.f, 0.f, 0.f);
    }
    __syncthreads();

    int fg = tid & 15;
    int ng = tid >> 4;
    float4 acc[8];
#pragma unroll
    for (int ii = 0; ii < 8; ii++) acc[ii] = make_float4(0.f, 0.f, 0.f, 0.f);

    for (int kg = 0; kg < 16; kg++) {
        float4 xv[8];
#pragma unroll
        for (int ii = 0; ii < 8; ii++) xv[ii] = sX[(ng + 16 * ii) * XSTRIDE + kg];
#pragma unroll
        for (int kk = 0; kk < 4; kk++) {
            float4 wv = sW[(4 * kg + kk) * 16 + fg];
#pragma unroll
            for (int ii = 0; ii < 8; ii++) {
                float xs = (kk == 0) ? xv[ii].x : (kk == 1) ? xv[ii].y
                         : (kk == 2) ? xv[ii].z : xv[ii].w;
                acc[ii].x += wv.x * xs;
                acc[ii].y += wv.y * xs;
                acc[ii].z += wv.z * xs;
                acc[ii].w += wv.w * xs;
            }
        }
    }

    float4* H4 = (float4*)Hn;
#pragma unroll
    for (int ii = 0; ii < 8; ii++) {
        int node = base + ng + 16 * ii;
        if (node < n) {
            float d = dinv[node];
            float4 o = acc[ii];
            o.x *= d; o.y *= d; o.z *= d; o.w *= d;
            H4[(size_t)node * 16 + fg] = o;
        }
    }
}

// ---------------- fused gather + epilogue: pure row gather, 2 edges in flight/lane ----------------
// OUT[i,:] = relu( dinv[i] * ( sum_{e:dst=i} Hn[src_e,:] + Hn[i,:] ) + b )
// wave per node; lane = g*8+f: 8 edge subgroups x 8 feature lanes; each lane
// processes edge pair (k, k+8) per iteration -> 4 independent 16 B loads in flight.
__global__ __launch_bounds__(256) void gather_fused(const int* __restrict__ rowptr,
                                                    const int* __restrict__ eidx,
                                                    const float* __restrict__ dinv,
                                                    const float* __restrict__ Hn,
                                                    const float* __restrict__ b,
                                                    float* __restrict__ OUT, int n) {
    int w = (blockIdx.x * blockDim.x + threadIdx.x) >> 6;
    int lane = threadIdx.x & 63;
    if (w >= n) return;
    int g = lane >> 3;      // edge subgroup 0..7
    int f = lane & 7;       // feature quad (covers quads f and f+8)
    int beg = rowptr[w], end = rowptr[w + 1];
    const char* Hb = (const char*)Hn;

    float4 a0 = make_float4(0.f, 0.f, 0.f, 0.f);
    float4 a1 = make_float4(0.f, 0.f, 0.f, 0.f);
    int k = beg + g;
    // pair loop: k and k+8 both valid
    for (; k + 8 < end; k += 16) {
        int o1 = eidx[k];
        int o2 = eidx[k + 8];
        float4 p0 = *(const float4*)(Hb + o1 + f * 16);
        float4 p1 = *(const float4*)(Hb + o1 + 128 + f * 16);
        float4 q0 = *(const float4*)(Hb + o2 + f * 16);
        float4 q1 = *(const float4*)(Hb + o2 + 128 + f * 16);
        a0.x += p0.x + q0.x; a0.y += p0.y + q0.y;
        a0.z += p0.z + q0.z; a0.w += p0.w + q0.w;
        a1.x += p1.x + q1.x; a1.y += p1.y + q1.y;
        a1.z += p1.z + q1.z; a1.w += p1.w + q1.w;
    }
    if (k < end) {  // leftover single edge for this subgroup
        int o1 = eidx[k];
        float4 p0 = *(const float4*)(Hb + o1 + f * 16);
        float4 p1 = *(const float4*)(Hb + o1 + 128 + f * 16);
        a0.x += p0.x; a0.y += p0.y; a0.z += p0.z; a0.w += p0.w;
        a1.x += p1.x; a1.y += p1.y; a1.z += p1.z; a1.w += p1.w;
    }
    // reduce across the 8 edge subgroups (lanes xor 8, 16, 32)
#pragma unroll
    for (int m = 8; m <= 32; m <<= 1) {
        a0.x += __shfl_xor(a0.x, m); a0.y += __shfl_xor(a0.y, m);
        a0.z += __shfl_xor(a0.z, m); a0.w += __shfl_xor(a0.w, m);
        a1.x += __shfl_xor(a1.x, m); a1.y += __shfl_xor(a1.y, m);
        a1.z += __shfl_xor(a1.z, m); a1.w += __shfl_xor(a1.w, m);
    }

    if (g == 0) {
        float di = dinv[w];
        const float4* H4 = (const float4*)Hn;
        float4 h0 = H4[(size_t)w * 16 + f];
        float4 h1 = H4[(size_t)w * 16 + 8 + f];
        float4 b0 = ((const float4*)b)[f];
        float4 b1 = ((const float4*)b)[8 + f];
        float4 o0, o1;
        o0.x = fmaxf(di * (a0.x + h0.x) + b0.x, 0.f);
        o0.y = fmaxf(di * (a0.y + h0.y) + b0.y, 0.f);
        o0.z = fmaxf(di * (a0.z + h0.z) + b0.z, 0.f);
        o0.w = fmaxf(di * (a0.w + h0.w) + b0.w, 0.f);
        o1.x = fmaxf(di * (a1.x + h1.x) + b1.x, 0.f);
        o1.y = fmaxf(di * (a1.y + h1.y) + b1.y, 0.f);
        o1.z = fmaxf(di * (a1.z + h1.z) + b1.z, 0.f);
        o1.w = fmaxf(di * (a1.w + h1.w) + b1.w, 0.f);
        ((float4*)OUT)[(size_t)w * 16 + f]     = o0;
        ((float4*)OUT)[(size_t)w * 16 + 8 + f] = o1;
    }
}

// ---------------- pooling: one block per graph, zero atomics ----------------
__global__ __launch_bounds__(256) void pool_graph(const float* __restrict__ H,
                                                  const int* __restrict__ batch,
                                                  const float* __restrict__ Wl,
                                                  const float* __restrict__ bl,
                                                  float* __restrict__ out) {
    int g = blockIdx.x;
    __shared__ int slo, shi;
    __shared__ float sWl[64];
    __shared__ float wsum[4];
    int tid = threadIdx.x;
    if (tid < 64) sWl[tid] = Wl[tid];
    if (tid == 0) {
        int a = 0, b = N_NODES;
        while (a < b) { int m = (a + b) >> 1; if (batch[m] < g) a = m + 1; else b = m; }
        slo = a;
        b = N_NODES;
        while (a < b) { int m = (a + b) >> 1; if (batch[m] < g + 1) a = m + 1; else b = m; }
        shi = a;
    }
    __syncthreads();
    int lo = slo, hi = shi;
    int lane = tid & 63, wave = tid >> 6;
    float acc = 0.f;
    for (int node = lo + wave; node < hi; node += 4)
        acc += H[(size_t)node * 64 + lane] * sWl[lane];
#pragma unroll
    for (int off = 32; off > 0; off >>= 1) acc += __shfl_down(acc, off);
    if (lane == 0) wsum[wave] = acc;
    __syncthreads();
    if (tid == 0) {
        float s = wsum[0] + wsum[1] + wsum[2] + wsum[3];
        float cnt = (float)(hi - lo);
        out[g] = s / fmaxf(cnt, 1.0f) + bl[0];
    }
}

extern "C" void kernel_launch(void* const* d_in, const int* in_sizes, int n_in,
                              void* d_out, int out_size, void* d_ws, size_t ws_size,
                              hipStream_t stream) {
    const float* x     = (const float*)d_in[0];
    const int*   src   = (const int*)d_in[1];
    const int*   dst   = (const int*)d_in[2];
    const int*   batch = (const int*)d_in[3];
    const float* W1 = (const float*)d_in[4];  const float* b1 = (const float*)d_in[5];
    const float* W2 = (const float*)d_in[6];  const float* b2 = (const float*)d_in[7];
    const float* W3 = (const float*)d_in[8];  const float* b3 = (const float*)d_in[9];
    const float* Wl = (const float*)d_in[10]; const float* bl = (const float*)d_in[11];
    float* out = (float*)d_out;

    char* ws = (char*)d_ws;
    float* A       = (float*)ws;                                 // N*F
    float* B       = A + (size_t)N_NODES * F;                    // N*F
    float* dinv    = B + (size_t)N_NODES * F;                    // N
    int*   cnt     = (int*)(dinv + N_NODES);                     // N
    int*   rowptr  = cnt + N_NODES;                              // N+1
    int*   parts   = rowptr + N_NODES + 1;                       // NBLK
    int*   rank    = parts + NBLK;                               // E
    int*   eidx    = rank + N_EDGES;                             // E

    const int GEMM_GRID     = (N_NODES + 127) / 128;             // 391
    const int EDGE_GRID     = (N_EDGES + 255) / 256;             // 3125
    const int NODEWAVE_GRID = (N_NODES * 64 + 255) / 256;        // 12500

    // ---- preprocessing: degrees + ranks + CSR-by-dst ----
    hipMemsetAsync(cnt, 0, N_NODES * sizeof(int), stream);
    hist_dst<<<EDGE_GRID, 256, 0, stream>>>(dst, cnt, rank, N_EDGES);
    scan_partial_sums<<<NBLK, 256, 0, stream>>>(cnt, parts);
    scan_partials<<<1, 256, 0, stream>>>(parts, rowptr);
    scan_write<<<NBLK, 256, 0, stream>>>(cnt, parts, rowptr, dinv);
    reorder_edges<<<EDGE_GRID, 256, 0, stream>>>(src, dst, rowptr, rank, eidx, N_EDGES);

    // ---- layer 1 ----
    gemm64_v<<<GEMM_GRID, 256, 0, stream>>>(x, W1, dinv, A, N_NODES);
    gather_fused<<<NODEWAVE_GRID, 256, 0, stream>>>(rowptr, eidx, dinv, A, b1, B, N_NODES);

    // ---- layer 2 ----
    gemm64_v<<<GEMM_GRID, 256, 0, stream>>>(B, W2, dinv, A, N_NODES);
    gather_fused<<<NODEWAVE_GRID, 256, 0, stream>>>(rowptr, eidx, dinv, A, b2, B, N_NODES);

    // ---- layer 3 ----
    gemm64_v<<<GEMM_GRID, 256, 0, stream>>>(B, W3, dinv, A, N_NODES);
    gather_fused<<<NODEWAVE_GRID, 256, 0, stream>>>(rowptr, eidx, dinv, A, b3, B, N_NODES);

    // ---- pooling + head ----
    pool_graph<<<N_GRAPHS, 256, 0, stream>>>(B, batch, Wl, bl, out);
}

// Round 8
// 293.122 us; speedup vs baseline: 3.2175x; 1.0271x over previous
//
#include <hip/hip_runtime.h>

#define N_NODES 50000
#define N_EDGES 800000
#define N_GRAPHS 256
#define F 64
#define NBUCK 196          // ceil(50000/256) coarse buckets (dst>>8)
#define P3_TILE 2048
#define P3_GRID ((N_EDGES + P3_TILE - 1) / P3_TILE)
#define BCAP 6144          // LDS staging cap per bucket (mean 4096, sd 64)

// ---------------- P1: coarse bucket histogram (LDS-staged) ----------------
__global__ __launch_bounds__(256) void bucket_hist(const int* __restrict__ dst,
                                                   int* __restrict__ bcnt) {
    __shared__ int h[NBUCK];
    int t = threadIdx.x;
    for (int i = t; i < NBUCK; i += 256) h[i] = 0;
    __syncthreads();
    for (int e = blockIdx.x * 256 + t; e < N_EDGES; e += gridDim.x * 256)
        atomicAdd(&h[dst[e] >> 8], 1);
    __syncthreads();
    for (int i = t; i < NBUCK; i += 256)
        if (h[i]) atomicAdd(&bcnt[i], h[i]);
}

// ---------------- P2: scan bucket counts -> bases + cursors ----------------
__global__ __launch_bounds__(256) void bucket_scan(const int* __restrict__ bcnt,
                                                   int* __restrict__ bbase,
                                                   int* __restrict__ bcur) {
    __shared__ int s[256];
    int t = threadIdx.x;
    int v = (t < NBUCK) ? bcnt[t] : 0;
    s[t] = v;
    __syncthreads();
    for (int off = 1; off < 256; off <<= 1) {
        int u = (t >= off) ? s[t - off] : 0;
        __syncthreads();
        s[t] += u;
        __syncthreads();
    }
    int excl = s[t] - v;
    if (t < NBUCK) { bbase[t] = excl; bcur[t] = excl; }
    if (t == 255) bbase[NBUCK] = s[255];
}

// ---------------- P3: partition edges into coarse buckets (run-clustered writes) ----------------
// pair = (src << 8) | (dst & 255); src < 65536 so pair < 2^24.
__global__ __launch_bounds__(256) void partition_edges(const int* __restrict__ src,
                                                       const int* __restrict__ dst,
                                                       int* __restrict__ bcur,
                                                       unsigned int* __restrict__ bpair) {
    __shared__ int bh[NBUCK], bloc[NBUCK], bpos[NBUCK];
    int t = threadIdx.x;
    int lo = blockIdx.x * P3_TILE;
    int hi = min(lo + P3_TILE, N_EDGES);
    for (int i = t; i < NBUCK; i += 256) { bh[i] = 0; bpos[i] = 0; }
    __syncthreads();
    for (int e = lo + t; e < hi; e += 256) atomicAdd(&bh[dst[e] >> 8], 1);
    __syncthreads();
    for (int i = t; i < NBUCK; i += 256)
        bloc[i] = bh[i] ? atomicAdd(&bcur[i], bh[i]) : 0;
    __syncthreads();
    for (int e = lo + t; e < hi; e += 256) {
        int d = dst[e];
        int b = d >> 8;
        int r = atomicAdd(&bpos[b], 1);
        bpair[bloc[b] + r] = ((unsigned)src[e] << 8) | (unsigned)(d & 255);
    }
}

// ---------------- P4: per-bucket LDS counting sort -> eidx, rowptr, dinv ----------------
__global__ __launch_bounds__(256) void bucket_sort(const unsigned int* __restrict__ bpair,
                                                   const int* __restrict__ bbase,
                                                   int* __restrict__ eidx,
                                                   int* __restrict__ rowptr,
                                                   float* __restrict__ dinv) {
    __shared__ int cnt[256], s[256], pos[256];
    __shared__ int lout[BCAP];
    int b = blockIdx.x, t = threadIdx.x;
    int base = bbase[b], bend = bbase[b + 1];
    int sz = bend - base;

    cnt[t] = 0;
    __syncthreads();
    for (int i = t; i < sz; i += 256) atomicAdd(&cnt[bpair[base + i] & 255], 1);
    __syncthreads();
    int v = cnt[t];
    s[t] = v;
    __syncthreads();
    for (int off = 1; off < 256; off <<= 1) {
        int u = (t >= off) ? s[t - off] : 0;
        __syncthreads();
        s[t] += u;
        __syncthreads();
    }
    int excl = s[t] - v;
    pos[t] = excl;
    int node = b * 256 + t;
    if (node < N_NODES) {
        rowptr[node] = base + excl;
        dinv[node] = 1.0f / sqrtf((float)v + 1.0f);   // +1 self-loop
    }
    if (b == NBUCK - 1 && t == 0) rowptr[N_NODES] = bend;
    __syncthreads();

    if (sz <= BCAP) {
        for (int i = t; i < sz; i += 256) {
            unsigned p = bpair[base + i];
            int r = atomicAdd(&pos[p & 255], 1);
            lout[r] = (int)(p & 0xFFFFFF00u);   // src byte offset (src*256)
        }
        __syncthreads();
        for (int i = t; i < sz; i += 256) eidx[base + i] = lout[i];
    } else {
        // fallback (statistically unreachable): direct scatter
        for (int i = t; i < sz; i += 256) {
            unsigned p = bpair[base + i];
            int r = atomicAdd(&pos[p & 255], 1);
            eidx[base + r] = (int)(p & 0xFFFFFF00u);
        }
    }
}

// ---------------- GEMM + dinv fold: Hn[i,:] = (X[i,:] @ W) * dinv[i] ----------------
#define XSTRIDE 17   // float4 stride pad
__global__ __launch_bounds__(256) void gemm64_v(const float* __restrict__ X,
                                                const float* __restrict__ W,
                                                const float* __restrict__ dinv,
                                                float* __restrict__ Hn, int n) {
    __shared__ float4 sW[64 * 16];        // sW[k*16 + fg] = W[k][4fg..4fg+3]
    __shared__ float4 sX[128 * XSTRIDE];  // sX[r*17 + kg] = X[base+r][4kg..4kg+3]
    int tid = threadIdx.x;
    int base = blockIdx.x * 128;

    const float4* W4 = (const float4*)W;
    for (int i = tid; i < 64 * 16; i += 256) sW[i] = W4[i];
    const float4* X4 = (const float4*)X;
    for (int i = tid; i < 128 * 16; i += 256) {
        int r = i >> 4, kg = i & 15;
        int node = base + r;
        sX[r * XSTRIDE + kg] = (node < n) ? X4[(size_t)node * 16 + kg]
                                          : make_float4(0.f, 0.f, 0.f, 0.f);
    }
    __syncthreads();

    int fg = tid & 15;
    int ng = tid >> 4;
    float4 acc[8];
#pragma unroll
    for (int ii = 0; ii < 8; ii++) acc[ii] = make_float4(0.f, 0.f, 0.f, 0.f);

    for (int kg = 0; kg < 16; kg++) {
        float4 xv[8];
#pragma unroll
        for (int ii = 0; ii < 8; ii++) xv[ii] = sX[(ng + 16 * ii) * XSTRIDE + kg];
#pragma unroll
        for (int kk = 0; kk < 4; kk++) {
            float4 wv = sW[(4 * kg + kk) * 16 + fg];
#pragma unroll
            for (int ii = 0; ii < 8; ii++) {
                float xs = (kk == 0) ? xv[ii].x : (kk == 1) ? xv[ii].y
                         : (kk == 2) ? xv[ii].z : xv[ii].w;
                acc[ii].x += wv.x * xs;
                acc[ii].y += wv.y * xs;
                acc[ii].z += wv.z * xs;
                acc[ii].w += wv.w * xs;
            }
        }
    }

    float4* H4 = (float4*)Hn;
#pragma unroll
    for (int ii = 0; ii < 8; ii++) {
        int node = base + ng + 16 * ii;
        if (node < n) {
            float d = dinv[node];
            float4 o = acc[ii];
            o.x *= d; o.y *= d; o.z *= d; o.w *= d;
            H4[(size_t)node * 16 + fg] = o;
        }
    }
}

// ---------------- fused gather + epilogue: pure row gather ----------------
// OUT[i,:] = relu( dinv[i] * ( sum_{e:dst=i} Hn[src_e,:] + Hn[i,:] ) + b )
__global__ __launch_bounds__(256) void gather_fused(const int* __restrict__ rowptr,
                                                    const int* __restrict__ eidx,
                                                    const float* __restrict__ dinv,
                                                    const float* __restrict__ Hn,
                                                    const float* __restrict__ b,
                                                    float* __restrict__ OUT, int n) {
    int w = (blockIdx.x * blockDim.x + threadIdx.x) >> 6;
    int lane = threadIdx.x & 63;
    if (w >= n) return;
    int g = lane >> 3;      // edge subgroup 0..7
    int f = lane & 7;       // feature quad (covers quads f and f+8)
    int beg = rowptr[w], end = rowptr[w + 1];
    const char* Hb = (const char*)Hn;

    float4 a0 = make_float4(0.f, 0.f, 0.f, 0.f);
    float4 a1 = make_float4(0.f, 0.f, 0.f, 0.f);
    int k = beg + g;
    for (; k + 8 < end; k += 16) {
        int o1 = eidx[k];
        int o2 = eidx[k + 8];
        float4 p0 = *(const float4*)(Hb + o1 + f * 16);
        float4 p1 = *(const float4*)(Hb + o1 + 128 + f * 16);
        float4 q0 = *(const float4*)(Hb + o2 + f * 16);
        float4 q1 = *(const float4*)(Hb + o2 + 128 + f * 16);
        a0.x += p0.x + q0.x; a0.y += p0.y + q0.y;
        a0.z += p0.z + q0.z; a0.w += p0.w + q0.w;
        a1.x += p1.x + q1.x; a1.y += p1.y + q1.y;
        a1.z += p1.z + q1.z; a1.w += p1.w + q1.w;
    }
    if (k < end) {
        int o1 = eidx[k];
        float4 p0 = *(const float4*)(Hb + o1 + f * 16);
        float4 p1 = *(const float4*)(Hb + o1 + 128 + f * 16);
        a0.x += p0.x; a0.y += p0.y; a0.z += p0.z; a0.w += p0.w;
        a1.x += p1.x; a1.y += p1.y; a1.z += p1.z; a1.w += p1.w;
    }
#pragma unroll
    for (int m = 8; m <= 32; m <<= 1) {
        a0.x += __shfl_xor(a0.x, m); a0.y += __shfl_xor(a0.y, m);
        a0.z += __shfl_xor(a0.z, m); a0.w += __shfl_xor(a0.w, m);
        a1.x += __shfl_xor(a1.x, m); a1.y += __shfl_xor(a1.y, m);
        a1.z += __shfl_xor(a1.z, m); a1.w += __shfl_xor(a1.w, m);
    }

    if (g == 0) {
        float di = dinv[w];
        const float4* H4 = (const float4*)Hn;
        float4 h0 = H4[(size_t)w * 16 + f];
        float4 h1 = H4[(size_t)w * 16 + 8 + f];
        float4 b0 = ((const float4*)b)[f];
        float4 b1 = ((const float4*)b)[8 + f];
        float4 o0, o1;
        o0.x = fmaxf(di * (a0.x + h0.x) + b0.x, 0.f);
        o0.y = fmaxf(di * (a0.y + h0.y) + b0.y, 0.f);
        o0.z = fmaxf(di * (a0.z + h0.z) + b0.z, 0.f);
        o0.w = fmaxf(di * (a0.w + h0.w) + b0.w, 0.f);
        o1.x = fmaxf(di * (a1.x + h1.x) + b1.x, 0.f);
        o1.y = fmaxf(di * (a1.y + h1.y) + b1.y, 0.f);
        o1.z = fmaxf(di * (a1.z + h1.z) + b1.z, 0.f);
        o1.w = fmaxf(di * (a1.w + h1.w) + b1.w, 0.f);
        ((float4*)OUT)[(size_t)w * 16 + f]     = o0;
        ((float4*)OUT)[(size_t)w * 16 + 8 + f] = o1;
    }
}

// ---------------- pooling: one block per graph, zero atomics ----------------
__global__ __launch_bounds__(256) void pool_graph(const float* __restrict__ H,
                                                  const int* __restrict__ batch,
                                                  const float* __restrict__ Wl,
                                                  const float* __restrict__ bl,
                                                  float* __restrict__ out) {
    int g = blockIdx.x;
    __shared__ int slo, shi;
    __shared__ float sWl[64];
    __shared__ float wsum[4];
    int tid = threadIdx.x;
    if (tid < 64) sWl[tid] = Wl[tid];
    if (tid == 0) {
        int a = 0, b = N_NODES;
        while (a < b) { int m = (a + b) >> 1; if (batch[m] < g) a = m + 1; else b = m; }
        slo = a;
        b = N_NODES;
        while (a < b) { int m = (a + b) >> 1; if (batch[m] < g + 1) a = m + 1; else b = m; }
        shi = a;
    }
    __syncthreads();
    int lo = slo, hi = shi;
    int lane = tid & 63, wave = tid >> 6;
    float acc = 0.f;
    for (int node = lo + wave; node < hi; node += 4)
        acc += H[(size_t)node * 64 + lane] * sWl[lane];
#pragma unroll
    for (int off = 32; off > 0; off >>= 1) acc += __shfl_down(acc, off);
    if (lane == 0) wsum[wave] = acc;
    __syncthreads();
    if (tid == 0) {
        float s = wsum[0] + wsum[1] + wsum[2] + wsum[3];
        float cnt = (float)(hi - lo);
        out[g] = s / fmaxf(cnt, 1.0f) + bl[0];
    }
}

extern "C" void kernel_launch(void* const* d_in, const int* in_sizes, int n_in,
                              void* d_out, int out_size, void* d_ws, size_t ws_size,
                              hipStream_t stream) {
    const float* x     = (const float*)d_in[0];
    const int*   src   = (const int*)d_in[1];
    const int*   dst   = (const int*)d_in[2];
    const int*   batch = (const int*)d_in[3];
    const float* W1 = (const float*)d_in[4];  const float* b1 = (const float*)d_in[5];
    const float* W2 = (const float*)d_in[6];  const float* b2 = (const float*)d_in[7];
    const float* W3 = (const float*)d_in[8];  const float* b3 = (const float*)d_in[9];
    const float* Wl = (const float*)d_in[10]; const float* bl = (const float*)d_in[11];
    float* out = (float*)d_out;

    char* ws = (char*)d_ws;
    float* A       = (float*)ws;                                 // N*F
    float* B       = A + (size_t)N_NODES * F;                    // N*F
    float* dinv    = B + (size_t)N_NODES * F;                    // N
    int*   rowptr  = (int*)(dinv + N_NODES);                     // N+1
    int*   bcnt    = rowptr + N_NODES + 1;                       // NBUCK
    int*   bbase   = bcnt + NBUCK;                               // NBUCK+1
    int*   bcur    = bbase + NBUCK + 1;                          // NBUCK
    unsigned int* bpair = (unsigned int*)(bcur + NBUCK);         // E
    int*   eidx    = (int*)(bpair + N_EDGES);                    // E

    const int GEMM_GRID     = (N_NODES + 127) / 128;             // 391
    const int NODEWAVE_GRID = (N_NODES * 64 + 255) / 256;        // 12500

    // ---- preprocessing: bucketed CSR build (rowptr, eidx, dinv) ----
    hipMemsetAsync(bcnt, 0, NBUCK * sizeof(int), stream);
    bucket_hist<<<256, 256, 0, stream>>>(dst, bcnt);
    bucket_scan<<<1, 256, 0, stream>>>(bcnt, bbase, bcur);
    partition_edges<<<P3_GRID, 256, 0, stream>>>(src, dst, bcur, bpair);
    bucket_sort<<<NBUCK, 256, 0, stream>>>(bpair, bbase, eidx, rowptr, dinv);

    // ---- layer 1 ----
    gemm64_v<<<GEMM_GRID, 256, 0, stream>>>(x, W1, dinv, A, N_NODES);
    gather_fused<<<NODEWAVE_GRID, 256, 0, stream>>>(rowptr, eidx, dinv, A, b1, B, N_NODES);

    // ---- layer 2 ----
    gemm64_v<<<GEMM_GRID, 256, 0, stream>>>(B, W2, dinv, A, N_NODES);
    gather_fused<<<NODEWAVE_GRID, 256, 0, stream>>>(rowptr, eidx, dinv, A, b2, B, N_NODES);

    // ---- layer 3 ----
    gemm64_v<<<GEMM_GRID, 256, 0, stream>>>(B, W3, dinv, A, N_NODES);
    gather_fused<<<NODEWAVE_GRID, 256, 0, stream>>>(rowptr, eidx, dinv, A, b3, B, N_NODES);

    // ---- pooling + head ----
    pool_graph<<<N_GRAPHS, 256, 0, stream>>>(B, batch, Wl, bl, out);
}

// Round 9
// 268.713 us; speedup vs baseline: 3.5097x; 1.0908x over previous
//
#include <hip/hip_runtime.h>

#define N_NODES 50000
#define N_EDGES 800000
#define N_GRAPHS 256
#define F 64
#define NBUCK 196          // ceil(50000/256) coarse buckets (dst>>8)
#define P3_TILE 2048
#define P3_GRID ((N_EDGES + P3_TILE - 1) / P3_TILE)
#define BCAP 6144          // LDS staging cap per bucket (mean 4096, sd 64)

// ---- bf16 helpers (RTN), all math stays f32 ----
__device__ __forceinline__ unsigned short f2bf(float f) {
    union { float f; unsigned u; } c; c.f = f;
    unsigned u = c.u + 0x7FFFu + ((c.u >> 16) & 1u);
    return (unsigned short)(u >> 16);
}
__device__ __forceinline__ float bfl(unsigned u) {   // low bf16 of a u32
    union { unsigned u; float f; } c; c.u = u << 16; return c.f;
}
__device__ __forceinline__ float bfh(unsigned u) {   // high bf16 of a u32
    union { unsigned u; float f; } c; c.u = u & 0xFFFF0000u; return c.f;
}

// ---------------- P1: coarse bucket histogram (LDS-staged) ----------------
__global__ __launch_bounds__(256) void bucket_hist(const int* __restrict__ dst,
                                                   int* __restrict__ bcnt) {
    __shared__ int h[NBUCK];
    int t = threadIdx.x;
    for (int i = t; i < NBUCK; i += 256) h[i] = 0;
    __syncthreads();
    for (int e = blockIdx.x * 256 + t; e < N_EDGES; e += gridDim.x * 256)
        atomicAdd(&h[dst[e] >> 8], 1);
    __syncthreads();
    for (int i = t; i < NBUCK; i += 256)
        if (h[i]) atomicAdd(&bcnt[i], h[i]);
}

// ---------------- P2: scan bucket counts -> bases + cursors ----------------
__global__ __launch_bounds__(256) void bucket_scan(const int* __restrict__ bcnt,
                                                   int* __restrict__ bbase,
                                                   int* __restrict__ bcur) {
    __shared__ int s[256];
    int t = threadIdx.x;
    int v = (t < NBUCK) ? bcnt[t] : 0;
    s[t] = v;
    __syncthreads();
    for (int off = 1; off < 256; off <<= 1) {
        int u = (t >= off) ? s[t - off] : 0;
        __syncthreads();
        s[t] += u;
        __syncthreads();
    }
    int excl = s[t] - v;
    if (t < NBUCK) { bbase[t] = excl; bcur[t] = excl; }
    if (t == 255) bbase[NBUCK] = s[255];
}

// ---------------- P3: partition edges into coarse buckets ----------------
// pair = (src << 8) | (dst & 255)
__global__ __launch_bounds__(256) void partition_edges(const int* __restrict__ src,
                                                       const int* __restrict__ dst,
                                                       int* __restrict__ bcur,
                                                       unsigned int* __restrict__ bpair) {
    __shared__ int bh[NBUCK], bloc[NBUCK], bpos[NBUCK];
    int t = threadIdx.x;
    int lo = blockIdx.x * P3_TILE;
    int hi = min(lo + P3_TILE, N_EDGES);
    for (int i = t; i < NBUCK; i += 256) { bh[i] = 0; bpos[i] = 0; }
    __syncthreads();
    for (int e = lo + t; e < hi; e += 256) atomicAdd(&bh[dst[e] >> 8], 1);
    __syncthreads();
    for (int i = t; i < NBUCK; i += 256)
        bloc[i] = bh[i] ? atomicAdd(&bcur[i], bh[i]) : 0;
    __syncthreads();
    for (int e = lo + t; e < hi; e += 256) {
        int d = dst[e];
        int b = d >> 8;
        int r = atomicAdd(&bpos[b], 1);
        bpair[bloc[b] + r] = ((unsigned)src[e] << 8) | (unsigned)(d & 255);
    }
}

// ---------------- P4: per-bucket LDS counting sort -> eidx (src*128), rowptr, dinv ----------------
__global__ __launch_bounds__(256) void bucket_sort(const unsigned int* __restrict__ bpair,
                                                   const int* __restrict__ bbase,
                                                   int* __restrict__ eidx,
                                                   int* __restrict__ rowptr,
                                                   float* __restrict__ dinv) {
    __shared__ int cnt[256], s[256], pos[256];
    __shared__ int lout[BCAP];
    int b = blockIdx.x, t = threadIdx.x;
    int base = bbase[b], bend = bbase[b + 1];
    int sz = bend - base;

    cnt[t] = 0;
    __syncthreads();
    for (int i = t; i < sz; i += 256) atomicAdd(&cnt[bpair[base + i] & 255], 1);
    __syncthreads();
    int v = cnt[t];
    s[t] = v;
    __syncthreads();
    for (int off = 1; off < 256; off <<= 1) {
        int u = (t >= off) ? s[t - off] : 0;
        __syncthreads();
        s[t] += u;
        __syncthreads();
    }
    int excl = s[t] - v;
    pos[t] = excl;
    int node = b * 256 + t;
    if (node < N_NODES) {
        rowptr[node] = base + excl;
        dinv[node] = 1.0f / sqrtf((float)v + 1.0f);   // +1 self-loop
    }
    if (b == NBUCK - 1 && t == 0) rowptr[N_NODES] = bend;
    __syncthreads();

    if (sz <= BCAP) {
        for (int i = t; i < sz; i += 256) {
            unsigned p = bpair[base + i];
            int r = atomicAdd(&pos[p & 255], 1);
            lout[r] = (int)((p >> 8) << 7);   // src byte offset (src*128, bf16 row)
        }
        __syncthreads();
        for (int i = t; i < sz; i += 256) eidx[base + i] = lout[i];
    } else {
        for (int i = t; i < sz; i += 256) {
            unsigned p = bpair[base + i];
            int r = atomicAdd(&pos[p & 255], 1);
            eidx[base + r] = (int)((p >> 8) << 7);
        }
    }
}

// ---------------- GEMM + dinv fold: Hn[i,:] = bf16( (X[i,:] @ W) * dinv[i] ) ----------------
// X is f32 (either global x or previous layer's f32 H). All math f32; store bf16.
#define XSTRIDE 17
__global__ __launch_bounds__(256) void gemm64_v(const float* __restrict__ X,
                                                const float* __restrict__ W,
                                                const float* __restrict__ dinv,
                                                unsigned short* __restrict__ Hn, int n) {
    __shared__ float4 sW[64 * 16];
    __shared__ float4 sX[128 * XSTRIDE];
    int tid = threadIdx.x;
    int base = blockIdx.x * 128;

    const float4* W4 = (const float4*)W;
    for (int i = tid; i < 64 * 16; i += 256) sW[i] = W4[i];
    const float4* X4 = (const float4*)X;
    for (int i = tid; i < 128 * 16; i += 256) {
        int r = i >> 4, kg = i & 15;
        int node = base + r;
        sX[r * XSTRIDE + kg] = (node < n) ? X4[(size_t)node * 16 + kg]
                                          : make_float4(0.f, 0.f, 0.f, 0.f);
    }
    __syncthreads();

    int fg = tid & 15;
    int ng = tid >> 4;
    float4 acc[8];
#pragma unroll
    for (int ii = 0; ii < 8; ii++) acc[ii] = make_float4(0.f, 0.f, 0.f, 0.f);

    for (int kg = 0; kg < 16; kg++) {
        float4 xv[8];
#pragma unroll
        for (int ii = 0; ii < 8; ii++) xv[ii] = sX[(ng + 16 * ii) * XSTRIDE + kg];
#pragma unroll
        for (int kk = 0; kk < 4; kk++) {
            float4 wv = sW[(4 * kg + kk) * 16 + fg];
#pragma unroll
            for (int ii = 0; ii < 8; ii++) {
                float xs = (kk == 0) ? xv[ii].x : (kk == 1) ? xv[ii].y
                         : (kk == 2) ? xv[ii].z : xv[ii].w;
                acc[ii].x += wv.x * xs;
                acc[ii].y += wv.y * xs;
                acc[ii].z += wv.z * xs;
                acc[ii].w += wv.w * xs;
            }
        }
    }

    ushort4* H4 = (ushort4*)Hn;   // row = 16 ushort4 units (64 bf16)
#pragma unroll
    for (int ii = 0; ii < 8; ii++) {
        int node = base + ng + 16 * ii;
        if (node < n) {
            float d = dinv[node];
            float4 o = acc[ii];
            ushort4 u;
            u.x = f2bf(o.x * d); u.y = f2bf(o.y * d);
            u.z = f2bf(o.z * d); u.w = f2bf(o.w * d);
            H4[(size_t)node * 16 + fg] = u;
        }
    }
}

// ---------------- fused gather + epilogue: bf16 rows, f32 accumulate ----------------
// OUT[i,:] = relu( dinv[i] * ( sum_{e:dst=i} Hn[src_e,:] + Hn[i,:] ) + b ), OUT f32
// wave per node; lane = g*8+f: 8 edge subgroups x 8 feature lanes; lane loads
// one 16 B chunk (8 bf16 = features 8f..8f+8) per edge; 2 edges in flight.
__global__ __launch_bounds__(256) void gather_fused(const int* __restrict__ rowptr,
                                                    const int* __restrict__ eidx,
                                                    const float* __restrict__ dinv,
                                                    const unsigned short* __restrict__ Hn,
                                                    const float* __restrict__ b,
                                                    float* __restrict__ OUT, int n) {
    int w = (blockIdx.x * blockDim.x + threadIdx.x) >> 6;
    int lane = threadIdx.x & 63;
    if (w >= n) return;
    int g = lane >> 3;      // edge subgroup 0..7
    int f = lane & 7;       // feature octet: features [8f, 8f+8)
    int beg = rowptr[w], end = rowptr[w + 1];
    const char* Hb = (const char*)Hn;

    float a0 = 0.f, a1 = 0.f, a2 = 0.f, a3 = 0.f;
    float a4 = 0.f, a5 = 0.f, a6 = 0.f, a7 = 0.f;
    int k = beg + g;
    for (; k + 8 < end; k += 16) {
        int o1 = eidx[k];
        int o2 = eidx[k + 8];
        uint4 p = *(const uint4*)(Hb + o1 + f * 16);
        uint4 q = *(const uint4*)(Hb + o2 + f * 16);
        a0 += bfl(p.x) + bfl(q.x); a1 += bfh(p.x) + bfh(q.x);
        a2 += bfl(p.y) + bfl(q.y); a3 += bfh(p.y) + bfh(q.y);
        a4 += bfl(p.z) + bfl(q.z); a5 += bfh(p.z) + bfh(q.z);
        a6 += bfl(p.w) + bfl(q.w); a7 += bfh(p.w) + bfh(q.w);
    }
    if (k < end) {
        int o1 = eidx[k];
        uint4 p = *(const uint4*)(Hb + o1 + f * 16);
        a0 += bfl(p.x); a1 += bfh(p.x);
        a2 += bfl(p.y); a3 += bfh(p.y);
        a4 += bfl(p.z); a5 += bfh(p.z);
        a6 += bfl(p.w); a7 += bfh(p.w);
    }
#pragma unroll
    for (int m = 8; m <= 32; m <<= 1) {
        a0 += __shfl_xor(a0, m); a1 += __shfl_xor(a1, m);
        a2 += __shfl_xor(a2, m); a3 += __shfl_xor(a3, m);
        a4 += __shfl_xor(a4, m); a5 += __shfl_xor(a5, m);
        a6 += __shfl_xor(a6, m); a7 += __shfl_xor(a7, m);
    }

    if (g == 0) {
        float di = dinv[w];
        uint4 hs = *(const uint4*)(Hb + (size_t)w * 128 + f * 16);
        float4 b0 = ((const float4*)b)[2 * f];
        float4 b1 = ((const float4*)b)[2 * f + 1];
        float4 o0, o1v;
        o0.x  = fmaxf(di * (a0 + bfl(hs.x)) + b0.x, 0.f);
        o0.y  = fmaxf(di * (a1 + bfh(hs.x)) + b0.y, 0.f);
        o0.z  = fmaxf(di * (a2 + bfl(hs.y)) + b0.z, 0.f);
        o0.w  = fmaxf(di * (a3 + bfh(hs.y)) + b0.w, 0.f);
        o1v.x = fmaxf(di * (a4 + bfl(hs.z)) + b1.x, 0.f);
        o1v.y = fmaxf(di * (a5 + bfh(hs.z)) + b1.y, 0.f);
        o1v.z = fmaxf(di * (a6 + bfl(hs.w)) + b1.z, 0.f);
        o1v.w = fmaxf(di * (a7 + bfh(hs.w)) + b1.w, 0.f);
        ((float4*)OUT)[(size_t)w * 16 + 2 * f]     = o0;
        ((float4*)OUT)[(size_t)w * 16 + 2 * f + 1] = o1v;
    }
}

// ---------------- pooling: one block per graph, zero atomics (f32 H) ----------------
__global__ __launch_bounds__(256) void pool_graph(const float* __restrict__ H,
                                                  const int* __restrict__ batch,
                                                  const float* __restrict__ Wl,
                                                  const float* __restrict__ bl,
                                                  float* __restrict__ out) {
    int g = blockIdx.x;
    __shared__ int slo, shi;
    __shared__ float sWl[64];
    __shared__ float wsum[4];
    int tid = threadIdx.x;
    if (tid < 64) sWl[tid] = Wl[tid];
    if (tid == 0) {
        int a = 0, b = N_NODES;
        while (a < b) { int m = (a + b) >> 1; if (batch[m] < g) a = m + 1; else b = m; }
        slo = a;
        b = N_NODES;
        while (a < b) { int m = (a + b) >> 1; if (batch[m] < g + 1) a = m + 1; else b = m; }
        shi = a;
    }
    __syncthreads();
    int lo = slo, hi = shi;
    int lane = tid & 63, wave = tid >> 6;
    float acc = 0.f;
    for (int node = lo + wave; node < hi; node += 4)
        acc += H[(size_t)node * 64 + lane] * sWl[lane];
#pragma unroll
    for (int off = 32; off > 0; off >>= 1) acc += __shfl_down(acc, off);
    if (lane == 0) wsum[wave] = acc;
    __syncthreads();
    if (tid == 0) {
        float s = wsum[0] + wsum[1] + wsum[2] + wsum[3];
        float cnt = (float)(hi - lo);
        out[g] = s / fmaxf(cnt, 1.0f) + bl[0];
    }
}

extern "C" void kernel_launch(void* const* d_in, const int* in_sizes, int n_in,
                              void* d_out, int out_size, void* d_ws, size_t ws_size,
                              hipStream_t stream) {
    const float* x     = (const float*)d_in[0];
    const int*   src   = (const int*)d_in[1];
    const int*   dst   = (const int*)d_in[2];
    const int*   batch = (const int*)d_in[3];
    const float* W1 = (const float*)d_in[4];  const float* b1 = (const float*)d_in[5];
    const float* W2 = (const float*)d_in[6];  const float* b2 = (const float*)d_in[7];
    const float* W3 = (const float*)d_in[8];  const float* b3 = (const float*)d_in[9];
    const float* Wl = (const float*)d_in[10]; const float* bl = (const float*)d_in[11];
    float* out = (float*)d_out;

    char* ws = (char*)d_ws;
    unsigned short* Abf = (unsigned short*)ws;                   // N*F bf16 (Hn)
    float* B       = (float*)(ws + (size_t)N_NODES * F * 2);     // N*F f32 (H)
    float* dinv    = B + (size_t)N_NODES * F;                    // N
    int*   rowptr  = (int*)(dinv + N_NODES);                     // N+1
    int*   bcnt    = rowptr + N_NODES + 1;                       // NBUCK
    int*   bbase   = bcnt + NBUCK;                               // NBUCK+1
    int*   bcur    = bbase + NBUCK + 1;                          // NBUCK
    unsigned int* bpair = (unsigned int*)(bcur + NBUCK);         // E
    int*   eidx    = (int*)(bpair + N_EDGES);                    // E

    const int GEMM_GRID     = (N_NODES + 127) / 128;             // 391
    const int NODEWAVE_GRID = (N_NODES * 64 + 255) / 256;        // 12500

    // ---- preprocessing: bucketed CSR build (rowptr, eidx, dinv) ----
    hipMemsetAsync(bcnt, 0, NBUCK * sizeof(int), stream);
    bucket_hist<<<256, 256, 0, stream>>>(dst, bcnt);
    bucket_scan<<<1, 256, 0, stream>>>(bcnt, bbase, bcur);
    partition_edges<<<P3_GRID, 256, 0, stream>>>(src, dst, bcur, bpair);
    bucket_sort<<<NBUCK, 256, 0, stream>>>(bpair, bbase, eidx, rowptr, dinv);

    // ---- layer 1 ----
    gemm64_v<<<GEMM_GRID, 256, 0, stream>>>(x, W1, dinv, Abf, N_NODES);
    gather_fused<<<NODEWAVE_GRID, 256, 0, stream>>>(rowptr, eidx, dinv, Abf, b1, B, N_NODES);

    // ---- layer 2 ----
    gemm64_v<<<GEMM_GRID, 256, 0, stream>>>(B, W2, dinv, Abf, N_NODES);
    gather_fused<<<NODEWAVE_GRID, 256, 0, stream>>>(rowptr, eidx, dinv, Abf, b2, B, N_NODES);

    // ---- layer 3 ----
    gemm64_v<<<GEMM_GRID, 256, 0, stream>>>(B, W3, dinv, Abf, N_NODES);
    gather_fused<<<NODEWAVE_GRID, 256, 0, stream>>>(rowptr, eidx, dinv, Abf, b3, B, N_NODES);

    // ---- pooling + head ----
    pool_graph<<<N_GRAPHS, 256, 0, stream>>>(B, batch, Wl, bl, out);
}